// Round 5
// baseline (174.199 us; speedup 1.0000x reference)
//
#include <hip/hip_runtime.h>
#include <hip/hip_bf16.h>

typedef unsigned short u16;
typedef __attribute__((ext_vector_type(8))) __bf16 bf16x8;
typedef __attribute__((ext_vector_type(4))) float f32x4;
typedef __attribute__((ext_vector_type(16))) float f32x16;

// Fragment-chunk layout for Qt/Vm (per batch, 4096x64 u16):
//   element (row n, channel c) -> ((n>>4)*8 + (c>>3))*128 + (n&15)*8 + (c&7)
//   (Vm stores V^T: "row" = channel, "col" = key.)
// Kt: TILE-MAJOR, stride 5120 u16 per 64-key tile: first 4096 = fragment-
//   chunk layout; last 1024 = "5th chunk" (ch64 = lw' = log2(1+beta*sig),
//   ch65 = 1.0). Q-side pairs it with constant frag {1.0, -17.25} so
//   s = K.q + lw' - 17.25 comes out of the MFMA; p = exp2(s); offset
//   cancels in the L1 renorm.
// attn r18: LDS-staged K/V (double-buffered 36.9 KB), global_load_lds w=16,
//   waves 0-1 stage K / 2-3 stage V; launch_bounds(256,3) -> 3 blocks/CU.
//   Rationale: r16 reg-prefetch was a no-op (attn ~33us flat) because the
//   kernel is occupancy-latency-bound at 2 blocks/CU; LDS staging cuts
//   per-wave VGPR ~90 and L2 traffic 4x, and the barrier-per-iter 2-phase
//   pipeline hides stage latency under the ~600cyc compute phase.
// r9 lesson: cross-block combine via threadfence+counter FAILED on HW
// (stale cross-XCD partials) - combine stays a separate kernel.
// r13/r15 ledger: total = ~43us ws-poison fill (fixed) + attn + ~61us
//   residual. R1 measured attn=53.2 directly; R2/R4 imply attn ~33.
//   If this round's total doesn't drop ~15us, the residual is harness
//   overhead and further attn work is pointless -> restructure instead.

#define NSPLIT 8

__device__ __forceinline__ u16 f2bf(float f) {
    unsigned u = __builtin_bit_cast(unsigned, f);
    u += 0x7FFFu + ((u >> 16) & 1u);
    return (u16)(u >> 16);
}
__device__ __forceinline__ float bf2f(u16 v) {
    unsigned u = ((unsigned)v) << 16;
    return __builtin_bit_cast(float, u);
}
__device__ __forceinline__ void gl_lds16(const u16* g, u16* l) {
    __builtin_amdgcn_global_load_lds(
        (const __attribute__((address_space(1))) unsigned*)g,
        (__attribute__((address_space(3))) unsigned*)l, 16, 0, 0);
}

// ------------------------------------------------------------ qkv + edge ---
__global__ __launch_bounds__(256) void qkv_edge_kernel(
    const float* __restrict__ x,
    const float* __restrict__ Wq, const float* __restrict__ bq,
    const float* __restrict__ Wk, const float* __restrict__ bk,
    const float* __restrict__ Wv, const float* __restrict__ bv,
    const float* __restrict__ We1, const float* __restrict__ be1,
    const float* __restrict__ bn_w, const float* __restrict__ bn_b,
    const float* __restrict__ bn_mean, const float* __restrict__ bn_var,
    const float* __restrict__ We2, const float* __restrict__ be2,
    const float* __restrict__ beta,
    u16* __restrict__ Qt, u16* __restrict__ Kt, u16* __restrict__ Vm)
{
    __shared__ __align__(16) u16 sm[33280];
    const int t = threadIdx.x;
    const int wv = t >> 6, lane = t & 63;
    const int quad = lane >> 4, l15 = lane & 15;

    if (blockIdx.x < 256) {
        // ---------------- qkv ----------------
        u16* Wl   = sm;                 // [3][64][72]
        u16* xt_s = sm + 13824;         // [64][66]
        u16* vt   = sm + 13824 + 4224;  // [64][72]
        const int b = blockIdx.x >> 6;
        const int n0 = (blockIdx.x & 63) << 6;

        const float* Wmat[3] = {Wq, Wk, Wv};
#pragma unroll
        for (int m = 0; m < 3; ++m)
#pragma unroll
            for (int i = 0; i < 4; ++i) {
                int u = t + i * 256;
                float4 w4 = *reinterpret_cast<const float4*>(Wmat[m] + u * 4);
                int row = u >> 4, col = (u & 15) * 4;
                uint2 pk;
                pk.x = (unsigned)f2bf(w4.x) | ((unsigned)f2bf(w4.y) << 16);
                pk.y = (unsigned)f2bf(w4.z) | ((unsigned)f2bf(w4.w) << 16);
                *reinterpret_cast<uint2*>(&Wl[(m * 64 + row) * 72 + col]) = pk;
            }
        for (int i = 0; i < 16; ++i) {
            int lin = t + i * 256;
            int c = lin >> 6, nn = lin & 63;
            xt_s[nn * 66 + c] = f2bf(x[(size_t)(b * 64 + c) * 4096 + n0 + nn]);
        }
        __syncthreads();

        bf16x8 bx[2];
#pragma unroll
        for (int h = 0; h < 2; ++h)
            bx[h] = *reinterpret_cast<const bf16x8*>(
                &xt_s[(wv * 16 + l15) * 66 + h * 32 + quad * 8]);

        f32x4 d[3][4];
#pragma unroll
        for (int m = 0; m < 3; ++m)
#pragma unroll
            for (int mt = 0; mt < 4; ++mt) d[m][mt] = (f32x4){0.f, 0.f, 0.f, 0.f};

#pragma unroll
        for (int h = 0; h < 2; ++h)
#pragma unroll
            for (int m = 0; m < 3; ++m)
#pragma unroll
                for (int mt = 0; mt < 4; ++mt) {
                    bf16x8 af = *reinterpret_cast<const bf16x8*>(
                        &Wl[(m * 64 + mt * 16 + l15) * 72 + h * 32 + quad * 8]);
                    d[m][mt] = __builtin_amdgcn_mfma_f32_16x16x32_bf16(af, bx[h], d[m][mt], 0, 0, 0);
                }

        const float* bias[3] = {bq, bk, bv};
        const float L2E = 1.44269504f;
#pragma unroll
        for (int m = 0; m < 3; ++m)
#pragma unroll
            for (int mt = 0; mt < 4; ++mt) {
                float4 bi = *reinterpret_cast<const float4*>(bias[m] + mt * 16 + quad * 4);
                d[m][mt][0] += bi.x; d[m][mt][1] += bi.y; d[m][mt][2] += bi.z; d[m][mt][3] += bi.w;
                if (m == 0) {
                    d[m][mt][0] *= L2E; d[m][mt][1] *= L2E;
                    d[m][mt][2] *= L2E; d[m][mt][3] *= L2E;
                }
            }

        // Q store: old global fragment-chunk layout
        const int rowchunk = (n0 >> 4) + wv;
        {
            u16* baseQ = Qt + (size_t)b * 262144;
#pragma unroll
            for (int mt = 0; mt < 4; ++mt) {
                uint2 pk;
                pk.x = (unsigned)f2bf(d[0][mt][0]) | ((unsigned)f2bf(d[0][mt][1]) << 16);
                pk.y = (unsigned)f2bf(d[0][mt][2]) | ((unsigned)f2bf(d[0][mt][3]) << 16);
                *reinterpret_cast<uint2*>(
                    baseQ + ((size_t)(rowchunk * 8 + mt * 2 + (quad >> 1))) * 128 +
                    l15 * 8 + (quad & 1) * 4) = pk;
            }
        }
        // K store: tile-major, stride 5120; within-tile chunk = wv*8 + c>>3
        {
            u16* baseK = Kt + (size_t)b * 327680 + (size_t)(n0 >> 6) * 5120;
#pragma unroll
            for (int mt = 0; mt < 4; ++mt) {
                uint2 pk;
                pk.x = (unsigned)f2bf(d[1][mt][0]) | ((unsigned)f2bf(d[1][mt][1]) << 16);
                pk.y = (unsigned)f2bf(d[1][mt][2]) | ((unsigned)f2bf(d[1][mt][3]) << 16);
                *reinterpret_cast<uint2*>(
                    baseK + (size_t)(wv * 8 + mt * 2 + (quad >> 1)) * 128 +
                    l15 * 8 + (quad & 1) * 4) = pk;
            }
        }
#pragma unroll
        for (int mt = 0; mt < 4; ++mt)
#pragma unroll
            for (int r = 0; r < 4; ++r)
                vt[(mt * 16 + quad * 4 + r) * 72 + wv * 16 + l15] = f2bf(d[2][mt][r]);
        __syncthreads();
        {
            u16* Vb_st = Vm + (size_t)b * 262144;
            const int kt = n0 >> 6;
#pragma unroll
            for (int i = 0; i < 2; ++i) {
                int unit = t + i * 256;
                int f = unit >> 7, hq = (unit >> 4) & 7, cl = unit & 15;
                const u16* src = &vt[(f * 16 + cl) * 72 + hq * 8];
                uint4 v4 = *reinterpret_cast<const uint4*>(src);
                *reinterpret_cast<uint4*>(
                    Vb_st + ((size_t)((kt * 4 + f) * 8 + hq)) * 128 + cl * 8) = v4;
            }
        }
    } else {
        // ---------------- edge ----------------
        u16* Ae_s = sm;            // [32][584]
        u16* xr_s = sm + 18688;    // [3][66][72]
        const int eb = blockIdx.x - 256;
        const int b = eb >> 6, h = eb & 63;

        if (t < 192) {
            int kh = t / 64, rem = t & 63;
            int col = (rem >> 5) * 65, ci2 = (rem & 31) * 2;
            *reinterpret_cast<unsigned*>(&xr_s[(kh * 66 + col) * 72 + ci2]) = 0u;
        }
#pragma unroll
        for (int i = 0; i < 18; ++i) {
            int u = t + i * 256;
            int ch = u / 144;
            int rem = u - ch * 144;
            int p = rem >> 4, cig = (rem & 15) * 4;
            const float* src = We1 + ch * 576 + cig * 9 + p;
            float a = src[0], b2 = src[9], c2 = src[18], d2 = src[27];
            uint2 pk;
            pk.x = (unsigned)f2bf(a) | ((unsigned)f2bf(b2) << 16);
            pk.y = (unsigned)f2bf(c2) | ((unsigned)f2bf(d2) << 16);
            *reinterpret_cast<uint2*>(&Ae_s[ch * 584 + p * 64 + cig]) = pk;
        }
#pragma unroll
        for (int i = 0; i < 12; ++i) {
            int u = t + i * 256;
            int w = u & 63, cig = (u >> 6) & 15, kh = u >> 10;
            int hs = h + kh - 1;
            float v0 = 0.f, v1 = 0.f, v2 = 0.f, v3 = 0.f;
            if ((unsigned)hs < 64u) {
                const float* src = x + ((size_t)(b * 64 + cig * 4) * 64 + hs) * 64 + w;
                v0 = src[0]; v1 = src[4096]; v2 = src[8192]; v3 = src[12288];
            }
            uint2 pk;
            pk.x = (unsigned)f2bf(v0) | ((unsigned)f2bf(v1) << 16);
            pk.y = (unsigned)f2bf(v2) | ((unsigned)f2bf(v3) << 16);
            *reinterpret_cast<uint2*>(&xr_s[(kh * 66 + w + 1) * 72 + cig * 4]) = pk;
        }
        __syncthreads();

        f32x4 e[2];
        e[0] = (f32x4){0.f, 0.f, 0.f, 0.f};
        e[1] = (f32x4){0.f, 0.f, 0.f, 0.f};
#pragma unroll
        for (int p = 0; p < 9; ++p) {
            const int kh = p / 3, kw = p - kh * 3;
#pragma unroll
            for (int half = 0; half < 2; ++half) {
                bf16x8 bfr = *reinterpret_cast<const bf16x8*>(
                    &xr_s[(kh * 66 + wv * 16 + l15 + kw) * 72 + half * 32 + quad * 8]);
#pragma unroll
                for (int mt = 0; mt < 2; ++mt) {
                    bf16x8 af = *reinterpret_cast<const bf16x8*>(
                        &Ae_s[(mt * 16 + l15) * 584 + p * 64 + half * 32 + quad * 8]);
                    e[mt] = __builtin_amdgcn_mfma_f32_16x16x32_bf16(af, bfr, e[mt], 0, 0, 0);
                }
            }
        }
        float partial = 0.f;
#pragma unroll
        for (int mt = 0; mt < 2; ++mt) {
            float4 bw = *reinterpret_cast<const float4*>(bn_w    + mt * 16 + quad * 4);
            float4 bb = *reinterpret_cast<const float4*>(bn_b    + mt * 16 + quad * 4);
            float4 bm = *reinterpret_cast<const float4*>(bn_mean + mt * 16 + quad * 4);
            float4 bv2 = *reinterpret_cast<const float4*>(bn_var + mt * 16 + quad * 4);
            float4 b1 = *reinterpret_cast<const float4*>(be1     + mt * 16 + quad * 4);
            float4 w2 = *reinterpret_cast<const float4*>(We2     + mt * 16 + quad * 4);
            float sc, sh;
            sc = bw.x * rsqrtf(bv2.x + 1e-5f); sh = (b1.x - bm.x) * sc + bb.x;
            partial += fmaxf(e[mt][0] * sc + sh, 0.f) * w2.x;
            sc = bw.y * rsqrtf(bv2.y + 1e-5f); sh = (b1.y - bm.y) * sc + bb.y;
            partial += fmaxf(e[mt][1] * sc + sh, 0.f) * w2.y;
            sc = bw.z * rsqrtf(bv2.z + 1e-5f); sh = (b1.z - bm.z) * sc + bb.z;
            partial += fmaxf(e[mt][2] * sc + sh, 0.f) * w2.z;
            sc = bw.w * rsqrtf(bv2.w + 1e-5f); sh = (b1.w - bm.w) * sc + bb.w;
            partial += fmaxf(e[mt][3] * sc + sh, 0.f) * w2.w;
        }
        partial += __shfl_xor(partial, 16);
        partial += __shfl_xor(partial, 32);
        if (lane < 16) {
            float s = partial + be2[0];
            float sg = 1.f / (1.f + __expf(-s));
            // 5th-chunk write: ch64 = lw' = log2(1+beta*sig), ch65 = 1.0.
            float lwp = __log2f(fmaxf(1.f + beta[0] * sg, 1e-20f));
            u16* k5 = Kt + (size_t)b * 327680 + (size_t)h * 5120 + 4096 +
                      (wv >> 1) * 512 + (wv & 1) * 256 + lane * 8;
            uint4 st0;
            st0.x = (unsigned)f2bf(lwp) | 0x3F800000u;  // {lw', 1.0}
            st0.y = 0u; st0.z = 0u; st0.w = 0u;
            *reinterpret_cast<uint4*>(k5) = st0;
            uint4 z; z.x = 0u; z.y = 0u; z.z = 0u; z.w = 0u;
            *reinterpret_cast<uint4*>(k5 + 128) = z;   // hi=1 half: zeros
        }
    }
}

// ------------------------------------------------------------- attention ---
// grid 128*NSPLIT(=1024); 256 thr = 4 waves x 32 q rows (QBLK=128), 8 kt-iters
// of 64 keys. 32x32x16 MFMA; swapped QK^T; P->B-frag via cvt_pk+permlane32.
// r18: double-buffered LDS staging of K(10KB incl lw chunk)+V(8KB) via
// global_load_lds w=16 (waves 0-1: K, waves 2-3: V); 2-phase pipeline
// [STAGE(next) | ds_read+MFMA(cur)] with one __syncthreads per iter (its
// implicit vmcnt(0) drain is the stage handshake). launch_bounds(256,3):
// VGPR<=170 -> 3 blocks/CU, LDS 3x36.9=110KB.
__global__ __launch_bounds__(256, 3) void attn_kernel(
    const u16* __restrict__ Qt, const u16* __restrict__ Kt,
    const u16* __restrict__ Vm,
    u16* __restrict__ O_part, float* __restrict__ l_part)
{
    constexpr int KT_ITERS = 64 / NSPLIT;   // 8
    __shared__ __align__(16) u16 kv[2][9216];   // [buf][ K 5120 | V 4096 ]

    // bijective XCD swizzle: 1024 blocks, 8 XCDs -> contiguous 128-block chunks
    const int bid = ((blockIdx.x & 7) << 7) + (blockIdx.x >> 3);
    const int t = threadIdx.x;
    const int qi = bid / NSPLIT;            // 0..127: (b, 128-q group)
    const int split = bid % NSPLIT;
    const int b = qi >> 5;
    const int n0 = (qi & 31) << 7;
    const int wv = t >> 6, lane = t & 63;
    const int l31 = lane & 31, hi = lane >> 5;
    const int i4 = (lane >> 4) & 1, l15 = lane & 15;

    const int kvoff = i4 * 1024 + hi * 128 + l15 * 8;   // within 4096-elem tile
    const int k5off = i4 * 256 + hi * 128 + l15 * 8;    // within 1024-elem chunk
    const u16* Qb  = Qt + (size_t)b * 262144;
    const u16* Ksp = Kt + (size_t)b * 327680 + (size_t)(split * KT_ITERS) * 5120;
    const u16* Vsp = Vm + (size_t)b * 262144 + (size_t)(split * KT_ITERS) * 4096;

    // Q B-frags: col=q=n0+wv*32+l31, k-chunk kc
    bf16x8 qf[4];
#pragma unroll
    for (int kc = 0; kc < 4; ++kc)
        qf[kc] = __builtin_bit_cast(bf16x8, *reinterpret_cast<const uint4*>(
            Qb + (size_t)(((n0 >> 4) + wv * 2) * 1024) + kvoff + kc * 256));
    // constant Q frag for the lw chunk: ch64 = 1.0, ch65 = -17.25 (bf16-exact)
    uint4 qc5u;
    qc5u.x = hi ? 0u : 0xC18A3F80u;
    qc5u.y = 0u; qc5u.z = 0u; qc5u.w = 0u;
    const bf16x8 qc5 = __builtin_bit_cast(bf16x8, qc5u);

    // stage tile `tile` (0..7) into buffer buf: waves 0-1 K (640 x 16B units),
    // waves 2-3 V (512 units). LDS dest linear in lane (global_load_lds rule).
    auto STAGE = [&](int buf, int tile) {
        if (wv < 2) {
            const u16* Kg = Ksp + (size_t)tile * 5120 + (wv * 320 + lane) * 8;
            u16* Kl = &kv[buf][(wv * 320 + lane) * 8];
#pragma unroll
            for (int i = 0; i < 5; ++i)
                gl_lds16(Kg + i * 512, Kl + i * 512);
        } else {
            const u16* Vg = Vsp + (size_t)tile * 4096 + ((wv - 2) * 256 + lane) * 8;
            u16* Vl = &kv[buf][5120 + ((wv - 2) * 256 + lane) * 8];
#pragma unroll
            for (int i = 0; i < 4; ++i)
                gl_lds16(Vg + i * 512, Vl + i * 512);
        }
    };

    f32x16 o[2];      // [c-tile of 32]: O^T[c][q]
#pragma unroll
    for (int ct = 0; ct < 2; ++ct)
#pragma unroll
        for (int i = 0; i < 16; ++i) o[ct][i] = 0.f;
    float lacc = 0.f;

    STAGE(0, 0);
    __syncthreads();    // implicit vmcnt(0): tile 0 resident

    int cur = 0;
    for (int kt = 0; kt < KT_ITERS; ++kt) {
        if (kt + 1 < KT_ITERS) STAGE(cur ^ 1, kt + 1);

        const u16* Kl = &kv[cur][0];
        const u16* Vl = &kv[cur][5120];

        // QK^T + softmax per 32-key tile; s = K.q + lw' - 17.25
        uint4 pbu[2][2];
#pragma unroll
        for (int tl = 0; tl < 2; ++tl) {
            bf16x8 k4 = *reinterpret_cast<const bf16x8*>(Kl + 4096 + tl * 512 + k5off);
            bf16x8 k0 = *reinterpret_cast<const bf16x8*>(Kl + tl * 2048 + kvoff);
            bf16x8 k1 = *reinterpret_cast<const bf16x8*>(Kl + tl * 2048 + 256 + kvoff);
            bf16x8 k2 = *reinterpret_cast<const bf16x8*>(Kl + tl * 2048 + 512 + kvoff);
            bf16x8 k3 = *reinterpret_cast<const bf16x8*>(Kl + tl * 2048 + 768 + kvoff);
            f32x16 s;
#pragma unroll
            for (int i = 0; i < 16; ++i) s[i] = 0.f;
            __builtin_amdgcn_s_setprio(1);
            s = __builtin_amdgcn_mfma_f32_32x32x16_bf16(k4, qc5,   s, 0, 0, 0);
            s = __builtin_amdgcn_mfma_f32_32x32x16_bf16(k0, qf[0], s, 0, 0, 0);
            s = __builtin_amdgcn_mfma_f32_32x32x16_bf16(k1, qf[1], s, 0, 0, 0);
            s = __builtin_amdgcn_mfma_f32_32x32x16_bf16(k2, qf[2], s, 0, 0, 0);
            s = __builtin_amdgcn_mfma_f32_32x32x16_bf16(k3, qf[3], s, 0, 0, 0);
            __builtin_amdgcn_s_setprio(0);

            float p[16];
#pragma unroll
            for (int i = 0; i < 16; ++i) p[i] = exp2f(s[i]);
            float t0 = (p[0] + p[1]) + (p[2] + p[3]);
            float t1 = (p[4] + p[5]) + (p[6] + p[7]);
            float t2 = (p[8] + p[9]) + (p[10] + p[11]);
            float t3 = (p[12] + p[13]) + (p[14] + p[15]);
            lacc += (t0 + t1) + (t2 + t3);
#pragma unroll
            for (int kc2 = 0; kc2 < 2; ++kc2) {
                int a0, a1, b0, b1;
                asm("v_cvt_pk_bf16_f32 %0, %1, %2" : "=v"(a0) : "v"(p[kc2 * 8 + 0]), "v"(p[kc2 * 8 + 1]));
                asm("v_cvt_pk_bf16_f32 %0, %1, %2" : "=v"(a1) : "v"(p[kc2 * 8 + 2]), "v"(p[kc2 * 8 + 3]));
                asm("v_cvt_pk_bf16_f32 %0, %1, %2" : "=v"(b0) : "v"(p[kc2 * 8 + 4]), "v"(p[kc2 * 8 + 5]));
                asm("v_cvt_pk_bf16_f32 %0, %1, %2" : "=v"(b1) : "v"(p[kc2 * 8 + 6]), "v"(p[kc2 * 8 + 7]));
                auto swA = __builtin_amdgcn_permlane32_swap(a0, b0, false, false);
                auto swB = __builtin_amdgcn_permlane32_swap(a1, b1, false, false);
                uint4 fr;
                fr.x = (unsigned)swA[0];   // keys hi*8 + 0,1
                fr.y = (unsigned)swB[0];   // keys hi*8 + 2,3
                fr.z = (unsigned)swA[1];   // keys hi*8 + 4,5
                fr.w = (unsigned)swB[1];   // keys hi*8 + 6,7
                pbu[tl][kc2] = fr;
            }
        }

        // PV: o[ct] += V-chunk x P-frag (V from LDS)
#pragma unroll
        for (int ct = 0; ct < 2; ++ct) {
            bf16x8 v0 = *reinterpret_cast<const bf16x8*>(Vl + ct * 2048 + kvoff);
            bf16x8 v1 = *reinterpret_cast<const bf16x8*>(Vl + ct * 2048 + 256 + kvoff);
            bf16x8 v2 = *reinterpret_cast<const bf16x8*>(Vl + ct * 2048 + 512 + kvoff);
            bf16x8 v3 = *reinterpret_cast<const bf16x8*>(Vl + ct * 2048 + 768 + kvoff);
            __builtin_amdgcn_s_setprio(1);
            o[ct] = __builtin_amdgcn_mfma_f32_32x32x16_bf16(v0,
                        __builtin_bit_cast(bf16x8, pbu[0][0]), o[ct], 0, 0, 0);
            o[ct] = __builtin_amdgcn_mfma_f32_32x32x16_bf16(v1,
                        __builtin_bit_cast(bf16x8, pbu[0][1]), o[ct], 0, 0, 0);
            o[ct] = __builtin_amdgcn_mfma_f32_32x32x16_bf16(v2,
                        __builtin_bit_cast(bf16x8, pbu[1][0]), o[ct], 0, 0, 0);
            o[ct] = __builtin_amdgcn_mfma_f32_32x32x16_bf16(v3,
                        __builtin_bit_cast(bf16x8, pbu[1][1]), o[ct], 0, 0, 0);
            __builtin_amdgcn_s_setprio(0);
        }

        __syncthreads();   // stage(next) drained + all waves done with cur
        cur ^= 1;
    }

    // l: lane (hi,q) holds half the keys' sum; combine halves via shfl_xor(32)
    float ltot = lacc + __shfl_xor(lacc, 32);
    if (lane < 32)
        l_part[(size_t)bid * 128 + wv * 32 + lane] = ltot;

    // O^T[c][q]: c = ct*32 + g*8 + hi*4 + rr, q = wv*32 + l31
    // store layout: O_part[bid*8192 + (c>>2)*512 + q*4 + (c&3)]
    const size_t pbase = (size_t)bid * 8192;
    const int q = wv * 32 + l31;
#pragma unroll
    for (int ct = 0; ct < 2; ++ct)
#pragma unroll
        for (int g = 0; g < 4; ++g) {
            int w0, w1;
            asm("v_cvt_pk_bf16_f32 %0, %1, %2" : "=v"(w0) : "v"(o[ct][4 * g + 0]), "v"(o[ct][4 * g + 1]));
            asm("v_cvt_pk_bf16_f32 %0, %1, %2" : "=v"(w1) : "v"(o[ct][4 * g + 2]), "v"(o[ct][4 * g + 3]));
            uint2 pk2;
            pk2.x = (unsigned)w0;
            pk2.y = (unsigned)w1;
            *reinterpret_cast<uint2*>(
                &O_part[pbase + (size_t)(ct * 8 + g * 2 + hi) * 512 + q * 4]) = pk2;
        }
}

// ---------------------------------------------------------------- combine --
// grid 512: one 32-q slice per block (2 blocks/CU). ab = attn qi (128-q),
// sub = which 32-q quarter. LDS stride 65 -> conflict-free scalar access.
__global__ __launch_bounds__(256) void combine_kernel(
    const u16* __restrict__ O_part, const float* __restrict__ l_part,
    const float* __restrict__ x, const float* __restrict__ g_gamma,
    float* __restrict__ out)
{
    __shared__ float ot[32 * 65];   // [q-local][c]
    __shared__ float ls[32];
    const int t = threadIdx.x;
    const int ab = blockIdx.x >> 2;
    const int sub = blockIdx.x & 3;
    const int b = ab >> 5;
    const int n0 = (ab & 31) << 7;
    const float gamma = g_gamma[0];

#pragma unroll
    for (int i = 0; i < 2; ++i) {
        int idx = t + i * 256;
        int c4 = idx >> 5, ql = idx & 31;
        float a0 = 0.f, a1 = 0.f, a2 = 0.f, a3 = 0.f;
#pragma unroll
        for (int s4 = 0; s4 < NSPLIT; ++s4) {
            uint2 u = *reinterpret_cast<const uint2*>(
                O_part + ((size_t)(ab * NSPLIT + s4)) * 8192 +
                (size_t)c4 * 512 + (sub * 32 + ql) * 4);
            a0 += bf2f((u16)(u.x & 0xFFFF));
            a1 += bf2f((u16)(u.x >> 16));
            a2 += bf2f((u16)(u.y & 0xFFFF));
            a3 += bf2f((u16)(u.y >> 16));
        }
        ot[ql * 65 + c4 * 4 + 0] = a0;
        ot[ql * 65 + c4 * 4 + 1] = a1;
        ot[ql * 65 + c4 * 4 + 2] = a2;
        ot[ql * 65 + c4 * 4 + 3] = a3;
    }
    if (t < 32) {
        float lsum = 0.f;
#pragma unroll
        for (int s4 = 0; s4 < NSPLIT; ++s4)
            lsum += l_part[((size_t)(ab * NSPLIT + s4)) * 128 + sub * 32 + t];
        ls[t] = gamma / fmaxf(lsum, 1e-30f);
    }
    __syncthreads();
    {
        const int c = t >> 2, seg = t & 3;
        const size_t gbase = ((size_t)(b * 64 + c)) * 4096 + n0 + sub * 32 + seg * 8;
#pragma unroll
        for (int j = 0; j < 2; ++j) {
            float4 xv = *reinterpret_cast<const float4*>(&x[gbase + j * 4]);
            float4 rv;
            int nl = seg * 8 + j * 4;
            rv.x = ot[(nl + 0) * 65 + c] * ls[nl + 0] + xv.x;
            rv.y = ot[(nl + 1) * 65 + c] * ls[nl + 1] + xv.y;
            rv.z = ot[(nl + 2) * 65 + c] * ls[nl + 2] + xv.z;
            rv.w = ot[(nl + 3) * 65 + c] * ls[nl + 3] + xv.w;
            *reinterpret_cast<float4*>(&out[gbase + j * 4]) = rv;
        }
    }
}

// ---------------------------------------------------------------- launch ---
extern "C" void kernel_launch(void* const* d_in, const int* in_sizes, int n_in,
                              void* d_out, int out_size, void* d_ws, size_t ws_size,
                              hipStream_t stream) {
    const float* x      = (const float*)d_in[0];
    const float* Wq     = (const float*)d_in[1];
    const float* bq     = (const float*)d_in[2];
    const float* Wk     = (const float*)d_in[3];
    const float* bk     = (const float*)d_in[4];
    const float* Wv     = (const float*)d_in[5];
    const float* bv     = (const float*)d_in[6];
    const float* We1    = (const float*)d_in[7];
    const float* be1    = (const float*)d_in[8];
    const float* bn_w   = (const float*)d_in[9];
    const float* bn_b   = (const float*)d_in[10];
    const float* bn_mean= (const float*)d_in[11];
    const float* bn_var = (const float*)d_in[12];
    const float* We2    = (const float*)d_in[13];
    const float* be2    = (const float*)d_in[14];
    const float* gamma  = (const float*)d_in[15];
    const float* beta   = (const float*)d_in[16];

    char* ws = (char*)d_ws;
    const size_t MB = 1024 * 1024;
    u16*   Qt     = (u16*)ws;                // [0, 2 MB)
    u16*   Kt     = (u16*)(ws + 2 * MB);     // [2, 4.625 MB) 4 x 327680 u16
    u16*   Vm     = (u16*)(ws + 5 * MB);     // [5, 7 MB)
    float* l_part = (float*)(ws + 7 * MB);   // 512 KB (1024 blk x 128)
    u16*   O_part = (u16*)(ws + 8 * MB);     // 16.78 MB (1024 x 8192)

    float* out = (float*)d_out;

    qkv_edge_kernel<<<dim3(512), dim3(256), 0, stream>>>(
        x, Wq, bq, Wk, bk, Wv, bv, We1, be1, bn_w, bn_b, bn_mean, bn_var,
        We2, be2, beta, Qt, Kt, Vm);
    attn_kernel<<<dim3(128 * NSPLIT), dim3(256), 0, stream>>>(
        Qt, Kt, Vm, O_part, l_part);
    combine_kernel<<<dim3(512), dim3(256), 0, stream>>>(
        O_part, l_part, x, gamma, out);
}

// Round 6
// 167.508 us; speedup vs baseline: 1.0399x; 1.0399x over previous
//
#include <hip/hip_runtime.h>
#include <hip/hip_bf16.h>

typedef unsigned short u16;
typedef __attribute__((ext_vector_type(8))) __bf16 bf16x8;
typedef __attribute__((ext_vector_type(4))) float f32x4;
typedef __attribute__((ext_vector_type(16))) float f32x16;

// Fragment-chunk layout for Qt/Vm (per batch, 4096x64 u16):
//   element (row n, channel c) -> ((n>>4)*8 + (c>>3))*128 + (n&15)*8 + (c&7)
//   (Vm stores V^T: "row" = channel, "col" = key.)
// Kt: TILE-MAJOR, stride 5120 u16 per 64-key tile: first 4096 = fragment-
//   chunk layout; last 1024 = "5th chunk" (ch64 = lw' = log2(1+beta*sig),
//   ch65 = 1.0). Q-side pairs it with constant frag {1.0, -17.25} so
//   s = K.q + lw' - 17.25 comes out of the MFMA; p = exp2(s); offset
//   cancels in the L1 renorm.
// attn r19 = r18 with ONE change: __launch_bounds__(256,4) instead of (256,3).
//   r18 post-mortem: VGPR_Count=84 (= the 512/6=85 six-wave boundary) with
//   FETCH 72MB / WRITE 138MB of scratch traffic -> the (256,3) bound (a
//   nonexistent 3-wave/SIMD occupancy step) made the compiler chase 6
//   waves/SIMD and SPILL the softmax state in the hot loop. Results were
//   bit-correct, so the global_load_lds staging layout is HW-verified.
//   (256,4) is a real step: cap 128 >= static pressure ~110 -> no spill,
//   4 blocks/CU (LDS 4x36.9=147.5KB <= 160), K/V L2 traffic stays deduped
//   4x vs r17 (147MB vs 590MB).
// r9 lesson: cross-block combine via threadfence+counter FAILED on HW
// (stale cross-XCD partials) - combine stays a separate kernel.
// r13/r15 ledger: total = ~43us ws-poison fill (fixed) + attn + ~61us
//   residual. attn history: r14 53 -> r15/r17 ~33 (reg-direct) -> r18 78
//   (spill). Revert target if this fails: r17 @ 136.0us total.

#define NSPLIT 8

__device__ __forceinline__ u16 f2bf(float f) {
    unsigned u = __builtin_bit_cast(unsigned, f);
    u += 0x7FFFu + ((u >> 16) & 1u);
    return (u16)(u >> 16);
}
__device__ __forceinline__ float bf2f(u16 v) {
    unsigned u = ((unsigned)v) << 16;
    return __builtin_bit_cast(float, u);
}
__device__ __forceinline__ void gl_lds16(const u16* g, u16* l) {
    __builtin_amdgcn_global_load_lds(
        (const __attribute__((address_space(1))) unsigned*)g,
        (__attribute__((address_space(3))) unsigned*)l, 16, 0, 0);
}

// ------------------------------------------------------------ qkv + edge ---
__global__ __launch_bounds__(256) void qkv_edge_kernel(
    const float* __restrict__ x,
    const float* __restrict__ Wq, const float* __restrict__ bq,
    const float* __restrict__ Wk, const float* __restrict__ bk,
    const float* __restrict__ Wv, const float* __restrict__ bv,
    const float* __restrict__ We1, const float* __restrict__ be1,
    const float* __restrict__ bn_w, const float* __restrict__ bn_b,
    const float* __restrict__ bn_mean, const float* __restrict__ bn_var,
    const float* __restrict__ We2, const float* __restrict__ be2,
    const float* __restrict__ beta,
    u16* __restrict__ Qt, u16* __restrict__ Kt, u16* __restrict__ Vm)
{
    __shared__ __align__(16) u16 sm[33280];
    const int t = threadIdx.x;
    const int wv = t >> 6, lane = t & 63;
    const int quad = lane >> 4, l15 = lane & 15;

    if (blockIdx.x < 256) {
        // ---------------- qkv ----------------
        u16* Wl   = sm;                 // [3][64][72]
        u16* xt_s = sm + 13824;         // [64][66]
        u16* vt   = sm + 13824 + 4224;  // [64][72]
        const int b = blockIdx.x >> 6;
        const int n0 = (blockIdx.x & 63) << 6;

        const float* Wmat[3] = {Wq, Wk, Wv};
#pragma unroll
        for (int m = 0; m < 3; ++m)
#pragma unroll
            for (int i = 0; i < 4; ++i) {
                int u = t + i * 256;
                float4 w4 = *reinterpret_cast<const float4*>(Wmat[m] + u * 4);
                int row = u >> 4, col = (u & 15) * 4;
                uint2 pk;
                pk.x = (unsigned)f2bf(w4.x) | ((unsigned)f2bf(w4.y) << 16);
                pk.y = (unsigned)f2bf(w4.z) | ((unsigned)f2bf(w4.w) << 16);
                *reinterpret_cast<uint2*>(&Wl[(m * 64 + row) * 72 + col]) = pk;
            }
        for (int i = 0; i < 16; ++i) {
            int lin = t + i * 256;
            int c = lin >> 6, nn = lin & 63;
            xt_s[nn * 66 + c] = f2bf(x[(size_t)(b * 64 + c) * 4096 + n0 + nn]);
        }
        __syncthreads();

        bf16x8 bx[2];
#pragma unroll
        for (int h = 0; h < 2; ++h)
            bx[h] = *reinterpret_cast<const bf16x8*>(
                &xt_s[(wv * 16 + l15) * 66 + h * 32 + quad * 8]);

        f32x4 d[3][4];
#pragma unroll
        for (int m = 0; m < 3; ++m)
#pragma unroll
            for (int mt = 0; mt < 4; ++mt) d[m][mt] = (f32x4){0.f, 0.f, 0.f, 0.f};

#pragma unroll
        for (int h = 0; h < 2; ++h)
#pragma unroll
            for (int m = 0; m < 3; ++m)
#pragma unroll
                for (int mt = 0; mt < 4; ++mt) {
                    bf16x8 af = *reinterpret_cast<const bf16x8*>(
                        &Wl[(m * 64 + mt * 16 + l15) * 72 + h * 32 + quad * 8]);
                    d[m][mt] = __builtin_amdgcn_mfma_f32_16x16x32_bf16(af, bx[h], d[m][mt], 0, 0, 0);
                }

        const float* bias[3] = {bq, bk, bv};
        const float L2E = 1.44269504f;
#pragma unroll
        for (int m = 0; m < 3; ++m)
#pragma unroll
            for (int mt = 0; mt < 4; ++mt) {
                float4 bi = *reinterpret_cast<const float4*>(bias[m] + mt * 16 + quad * 4);
                d[m][mt][0] += bi.x; d[m][mt][1] += bi.y; d[m][mt][2] += bi.z; d[m][mt][3] += bi.w;
                if (m == 0) {
                    d[m][mt][0] *= L2E; d[m][mt][1] *= L2E;
                    d[m][mt][2] *= L2E; d[m][mt][3] *= L2E;
                }
            }

        // Q store: old global fragment-chunk layout
        const int rowchunk = (n0 >> 4) + wv;
        {
            u16* baseQ = Qt + (size_t)b * 262144;
#pragma unroll
            for (int mt = 0; mt < 4; ++mt) {
                uint2 pk;
                pk.x = (unsigned)f2bf(d[0][mt][0]) | ((unsigned)f2bf(d[0][mt][1]) << 16);
                pk.y = (unsigned)f2bf(d[0][mt][2]) | ((unsigned)f2bf(d[0][mt][3]) << 16);
                *reinterpret_cast<uint2*>(
                    baseQ + ((size_t)(rowchunk * 8 + mt * 2 + (quad >> 1))) * 128 +
                    l15 * 8 + (quad & 1) * 4) = pk;
            }
        }
        // K store: tile-major, stride 5120; within-tile chunk = wv*8 + c>>3
        {
            u16* baseK = Kt + (size_t)b * 327680 + (size_t)(n0 >> 6) * 5120;
#pragma unroll
            for (int mt = 0; mt < 4; ++mt) {
                uint2 pk;
                pk.x = (unsigned)f2bf(d[1][mt][0]) | ((unsigned)f2bf(d[1][mt][1]) << 16);
                pk.y = (unsigned)f2bf(d[1][mt][2]) | ((unsigned)f2bf(d[1][mt][3]) << 16);
                *reinterpret_cast<uint2*>(
                    baseK + (size_t)(wv * 8 + mt * 2 + (quad >> 1)) * 128 +
                    l15 * 8 + (quad & 1) * 4) = pk;
            }
        }
#pragma unroll
        for (int mt = 0; mt < 4; ++mt)
#pragma unroll
            for (int r = 0; r < 4; ++r)
                vt[(mt * 16 + quad * 4 + r) * 72 + wv * 16 + l15] = f2bf(d[2][mt][r]);
        __syncthreads();
        {
            u16* Vb_st = Vm + (size_t)b * 262144;
            const int kt = n0 >> 6;
#pragma unroll
            for (int i = 0; i < 2; ++i) {
                int unit = t + i * 256;
                int f = unit >> 7, hq = (unit >> 4) & 7, cl = unit & 15;
                const u16* src = &vt[(f * 16 + cl) * 72 + hq * 8];
                uint4 v4 = *reinterpret_cast<const uint4*>(src);
                *reinterpret_cast<uint4*>(
                    Vb_st + ((size_t)((kt * 4 + f) * 8 + hq)) * 128 + cl * 8) = v4;
            }
        }
    } else {
        // ---------------- edge ----------------
        u16* Ae_s = sm;            // [32][584]
        u16* xr_s = sm + 18688;    // [3][66][72]
        const int eb = blockIdx.x - 256;
        const int b = eb >> 6, h = eb & 63;

        if (t < 192) {
            int kh = t / 64, rem = t & 63;
            int col = (rem >> 5) * 65, ci2 = (rem & 31) * 2;
            *reinterpret_cast<unsigned*>(&xr_s[(kh * 66 + col) * 72 + ci2]) = 0u;
        }
#pragma unroll
        for (int i = 0; i < 18; ++i) {
            int u = t + i * 256;
            int ch = u / 144;
            int rem = u - ch * 144;
            int p = rem >> 4, cig = (rem & 15) * 4;
            const float* src = We1 + ch * 576 + cig * 9 + p;
            float a = src[0], b2 = src[9], c2 = src[18], d2 = src[27];
            uint2 pk;
            pk.x = (unsigned)f2bf(a) | ((unsigned)f2bf(b2) << 16);
            pk.y = (unsigned)f2bf(c2) | ((unsigned)f2bf(d2) << 16);
            *reinterpret_cast<uint2*>(&Ae_s[ch * 584 + p * 64 + cig]) = pk;
        }
#pragma unroll
        for (int i = 0; i < 12; ++i) {
            int u = t + i * 256;
            int w = u & 63, cig = (u >> 6) & 15, kh = u >> 10;
            int hs = h + kh - 1;
            float v0 = 0.f, v1 = 0.f, v2 = 0.f, v3 = 0.f;
            if ((unsigned)hs < 64u) {
                const float* src = x + ((size_t)(b * 64 + cig * 4) * 64 + hs) * 64 + w;
                v0 = src[0]; v1 = src[4096]; v2 = src[8192]; v3 = src[12288];
            }
            uint2 pk;
            pk.x = (unsigned)f2bf(v0) | ((unsigned)f2bf(v1) << 16);
            pk.y = (unsigned)f2bf(v2) | ((unsigned)f2bf(v3) << 16);
            *reinterpret_cast<uint2*>(&xr_s[(kh * 66 + w + 1) * 72 + cig * 4]) = pk;
        }
        __syncthreads();

        f32x4 e[2];
        e[0] = (f32x4){0.f, 0.f, 0.f, 0.f};
        e[1] = (f32x4){0.f, 0.f, 0.f, 0.f};
#pragma unroll
        for (int p = 0; p < 9; ++p) {
            const int kh = p / 3, kw = p - kh * 3;
#pragma unroll
            for (int half = 0; half < 2; ++half) {
                bf16x8 bfr = *reinterpret_cast<const bf16x8*>(
                    &xr_s[(kh * 66 + wv * 16 + l15 + kw) * 72 + half * 32 + quad * 8]);
#pragma unroll
                for (int mt = 0; mt < 2; ++mt) {
                    bf16x8 af = *reinterpret_cast<const bf16x8*>(
                        &Ae_s[(mt * 16 + l15) * 584 + p * 64 + half * 32 + quad * 8]);
                    e[mt] = __builtin_amdgcn_mfma_f32_16x16x32_bf16(af, bfr, e[mt], 0, 0, 0);
                }
            }
        }
        float partial = 0.f;
#pragma unroll
        for (int mt = 0; mt < 2; ++mt) {
            float4 bw = *reinterpret_cast<const float4*>(bn_w    + mt * 16 + quad * 4);
            float4 bb = *reinterpret_cast<const float4*>(bn_b    + mt * 16 + quad * 4);
            float4 bm = *reinterpret_cast<const float4*>(bn_mean + mt * 16 + quad * 4);
            float4 bv2 = *reinterpret_cast<const float4*>(bn_var + mt * 16 + quad * 4);
            float4 b1 = *reinterpret_cast<const float4*>(be1     + mt * 16 + quad * 4);
            float4 w2 = *reinterpret_cast<const float4*>(We2     + mt * 16 + quad * 4);
            float sc, sh;
            sc = bw.x * rsqrtf(bv2.x + 1e-5f); sh = (b1.x - bm.x) * sc + bb.x;
            partial += fmaxf(e[mt][0] * sc + sh, 0.f) * w2.x;
            sc = bw.y * rsqrtf(bv2.y + 1e-5f); sh = (b1.y - bm.y) * sc + bb.y;
            partial += fmaxf(e[mt][1] * sc + sh, 0.f) * w2.y;
            sc = bw.z * rsqrtf(bv2.z + 1e-5f); sh = (b1.z - bm.z) * sc + bb.z;
            partial += fmaxf(e[mt][2] * sc + sh, 0.f) * w2.z;
            sc = bw.w * rsqrtf(bv2.w + 1e-5f); sh = (b1.w - bm.w) * sc + bb.w;
            partial += fmaxf(e[mt][3] * sc + sh, 0.f) * w2.w;
        }
        partial += __shfl_xor(partial, 16);
        partial += __shfl_xor(partial, 32);
        if (lane < 16) {
            float s = partial + be2[0];
            float sg = 1.f / (1.f + __expf(-s));
            // 5th-chunk write: ch64 = lw' = log2(1+beta*sig), ch65 = 1.0.
            float lwp = __log2f(fmaxf(1.f + beta[0] * sg, 1e-20f));
            u16* k5 = Kt + (size_t)b * 327680 + (size_t)h * 5120 + 4096 +
                      (wv >> 1) * 512 + (wv & 1) * 256 + lane * 8;
            uint4 st0;
            st0.x = (unsigned)f2bf(lwp) | 0x3F800000u;  // {lw', 1.0}
            st0.y = 0u; st0.z = 0u; st0.w = 0u;
            *reinterpret_cast<uint4*>(k5) = st0;
            uint4 z; z.x = 0u; z.y = 0u; z.z = 0u; z.w = 0u;
            *reinterpret_cast<uint4*>(k5 + 128) = z;   // hi=1 half: zeros
        }
    }
}

// ------------------------------------------------------------- attention ---
// grid 128*NSPLIT(=1024); 256 thr = 4 waves x 32 q rows (QBLK=128), 8 kt-iters
// of 64 keys. 32x32x16 MFMA; swapped QK^T; P->B-frag via cvt_pk+permlane32.
// r19: double-buffered LDS staging of K(10KB incl lw chunk)+V(8KB) via
// global_load_lds w=16 (waves 0-1: K, waves 2-3: V); 2-phase pipeline
// [STAGE(next) | ds_read+MFMA(cur)] with one __syncthreads per iter (its
// implicit vmcnt(0) drain is the stage handshake). launch_bounds(256,4):
// a REAL occupancy step (4 waves/SIMD, cap 128 >= ~110 static pressure);
// (256,3) made the compiler chase the 85-reg 6-wave boundary and spill.
__global__ __launch_bounds__(256, 4) void attn_kernel(
    const u16* __restrict__ Qt, const u16* __restrict__ Kt,
    const u16* __restrict__ Vm,
    u16* __restrict__ O_part, float* __restrict__ l_part)
{
    constexpr int KT_ITERS = 64 / NSPLIT;   // 8
    __shared__ __align__(16) u16 kv[2][9216];   // [buf][ K 5120 | V 4096 ]

    // bijective XCD swizzle: 1024 blocks, 8 XCDs -> contiguous 128-block chunks
    const int bid = ((blockIdx.x & 7) << 7) + (blockIdx.x >> 3);
    const int t = threadIdx.x;
    const int qi = bid / NSPLIT;            // 0..127: (b, 128-q group)
    const int split = bid % NSPLIT;
    const int b = qi >> 5;
    const int n0 = (qi & 31) << 7;
    const int wv = t >> 6, lane = t & 63;
    const int l31 = lane & 31, hi = lane >> 5;
    const int i4 = (lane >> 4) & 1, l15 = lane & 15;

    const int kvoff = i4 * 1024 + hi * 128 + l15 * 8;   // within 4096-elem tile
    const int k5off = i4 * 256 + hi * 128 + l15 * 8;    // within 1024-elem chunk
    const u16* Qb  = Qt + (size_t)b * 262144;
    const u16* Ksp = Kt + (size_t)b * 327680 + (size_t)(split * KT_ITERS) * 5120;
    const u16* Vsp = Vm + (size_t)b * 262144 + (size_t)(split * KT_ITERS) * 4096;

    // Q B-frags: col=q=n0+wv*32+l31, k-chunk kc
    bf16x8 qf[4];
#pragma unroll
    for (int kc = 0; kc < 4; ++kc)
        qf[kc] = __builtin_bit_cast(bf16x8, *reinterpret_cast<const uint4*>(
            Qb + (size_t)(((n0 >> 4) + wv * 2) * 1024) + kvoff + kc * 256));
    // constant Q frag for the lw chunk: ch64 = 1.0, ch65 = -17.25 (bf16-exact)
    uint4 qc5u;
    qc5u.x = hi ? 0u : 0xC18A3F80u;
    qc5u.y = 0u; qc5u.z = 0u; qc5u.w = 0u;
    const bf16x8 qc5 = __builtin_bit_cast(bf16x8, qc5u);

    // stage tile `tile` (0..7) into buffer buf: waves 0-1 K (640 x 16B units),
    // waves 2-3 V (512 units). LDS dest linear in lane (global_load_lds rule).
    auto STAGE = [&](int buf, int tile) {
        if (wv < 2) {
            const u16* Kg = Ksp + (size_t)tile * 5120 + (wv * 320 + lane) * 8;
            u16* Kl = &kv[buf][(wv * 320 + lane) * 8];
#pragma unroll
            for (int i = 0; i < 5; ++i)
                gl_lds16(Kg + i * 512, Kl + i * 512);
        } else {
            const u16* Vg = Vsp + (size_t)tile * 4096 + ((wv - 2) * 256 + lane) * 8;
            u16* Vl = &kv[buf][5120 + ((wv - 2) * 256 + lane) * 8];
#pragma unroll
            for (int i = 0; i < 4; ++i)
                gl_lds16(Vg + i * 512, Vl + i * 512);
        }
    };

    f32x16 o[2];      // [c-tile of 32]: O^T[c][q]
#pragma unroll
    for (int ct = 0; ct < 2; ++ct)
#pragma unroll
        for (int i = 0; i < 16; ++i) o[ct][i] = 0.f;
    float lacc = 0.f;

    STAGE(0, 0);
    __syncthreads();    // implicit vmcnt(0): tile 0 resident

    int cur = 0;
    for (int kt = 0; kt < KT_ITERS; ++kt) {
        if (kt + 1 < KT_ITERS) STAGE(cur ^ 1, kt + 1);

        const u16* Kl = &kv[cur][0];
        const u16* Vl = &kv[cur][5120];

        // QK^T + softmax per 32-key tile; s = K.q + lw' - 17.25
        uint4 pbu[2][2];
#pragma unroll
        for (int tl = 0; tl < 2; ++tl) {
            bf16x8 k4 = *reinterpret_cast<const bf16x8*>(Kl + 4096 + tl * 512 + k5off);
            bf16x8 k0 = *reinterpret_cast<const bf16x8*>(Kl + tl * 2048 + kvoff);
            bf16x8 k1 = *reinterpret_cast<const bf16x8*>(Kl + tl * 2048 + 256 + kvoff);
            bf16x8 k2 = *reinterpret_cast<const bf16x8*>(Kl + tl * 2048 + 512 + kvoff);
            bf16x8 k3 = *reinterpret_cast<const bf16x8*>(Kl + tl * 2048 + 768 + kvoff);
            f32x16 s;
#pragma unroll
            for (int i = 0; i < 16; ++i) s[i] = 0.f;
            __builtin_amdgcn_s_setprio(1);
            s = __builtin_amdgcn_mfma_f32_32x32x16_bf16(k4, qc5,   s, 0, 0, 0);
            s = __builtin_amdgcn_mfma_f32_32x32x16_bf16(k0, qf[0], s, 0, 0, 0);
            s = __builtin_amdgcn_mfma_f32_32x32x16_bf16(k1, qf[1], s, 0, 0, 0);
            s = __builtin_amdgcn_mfma_f32_32x32x16_bf16(k2, qf[2], s, 0, 0, 0);
            s = __builtin_amdgcn_mfma_f32_32x32x16_bf16(k3, qf[3], s, 0, 0, 0);
            __builtin_amdgcn_s_setprio(0);

            float p[16];
#pragma unroll
            for (int i = 0; i < 16; ++i) p[i] = exp2f(s[i]);
            float t0 = (p[0] + p[1]) + (p[2] + p[3]);
            float t1 = (p[4] + p[5]) + (p[6] + p[7]);
            float t2 = (p[8] + p[9]) + (p[10] + p[11]);
            float t3 = (p[12] + p[13]) + (p[14] + p[15]);
            lacc += (t0 + t1) + (t2 + t3);
#pragma unroll
            for (int kc2 = 0; kc2 < 2; ++kc2) {
                int a0, a1, b0, b1;
                asm("v_cvt_pk_bf16_f32 %0, %1, %2" : "=v"(a0) : "v"(p[kc2 * 8 + 0]), "v"(p[kc2 * 8 + 1]));
                asm("v_cvt_pk_bf16_f32 %0, %1, %2" : "=v"(a1) : "v"(p[kc2 * 8 + 2]), "v"(p[kc2 * 8 + 3]));
                asm("v_cvt_pk_bf16_f32 %0, %1, %2" : "=v"(b0) : "v"(p[kc2 * 8 + 4]), "v"(p[kc2 * 8 + 5]));
                asm("v_cvt_pk_bf16_f32 %0, %1, %2" : "=v"(b1) : "v"(p[kc2 * 8 + 6]), "v"(p[kc2 * 8 + 7]));
                auto swA = __builtin_amdgcn_permlane32_swap(a0, b0, false, false);
                auto swB = __builtin_amdgcn_permlane32_swap(a1, b1, false, false);
                uint4 fr;
                fr.x = (unsigned)swA[0];   // keys hi*8 + 0,1
                fr.y = (unsigned)swB[0];   // keys hi*8 + 2,3
                fr.z = (unsigned)swA[1];   // keys hi*8 + 4,5
                fr.w = (unsigned)swB[1];   // keys hi*8 + 6,7
                pbu[tl][kc2] = fr;
            }
        }

        // PV: o[ct] += V-chunk x P-frag (V from LDS)
#pragma unroll
        for (int ct = 0; ct < 2; ++ct) {
            bf16x8 v0 = *reinterpret_cast<const bf16x8*>(Vl + ct * 2048 + kvoff);
            bf16x8 v1 = *reinterpret_cast<const bf16x8*>(Vl + ct * 2048 + 256 + kvoff);
            bf16x8 v2 = *reinterpret_cast<const bf16x8*>(Vl + ct * 2048 + 512 + kvoff);
            bf16x8 v3 = *reinterpret_cast<const bf16x8*>(Vl + ct * 2048 + 768 + kvoff);
            __builtin_amdgcn_s_setprio(1);
            o[ct] = __builtin_amdgcn_mfma_f32_32x32x16_bf16(v0,
                        __builtin_bit_cast(bf16x8, pbu[0][0]), o[ct], 0, 0, 0);
            o[ct] = __builtin_amdgcn_mfma_f32_32x32x16_bf16(v1,
                        __builtin_bit_cast(bf16x8, pbu[0][1]), o[ct], 0, 0, 0);
            o[ct] = __builtin_amdgcn_mfma_f32_32x32x16_bf16(v2,
                        __builtin_bit_cast(bf16x8, pbu[1][0]), o[ct], 0, 0, 0);
            o[ct] = __builtin_amdgcn_mfma_f32_32x32x16_bf16(v3,
                        __builtin_bit_cast(bf16x8, pbu[1][1]), o[ct], 0, 0, 0);
            __builtin_amdgcn_s_setprio(0);
        }

        __syncthreads();   // stage(next) drained + all waves done with cur
        cur ^= 1;
    }

    // l: lane (hi,q) holds half the keys' sum; combine halves via shfl_xor(32)
    float ltot = lacc + __shfl_xor(lacc, 32);
    if (lane < 32)
        l_part[(size_t)bid * 128 + wv * 32 + lane] = ltot;

    // O^T[c][q]: c = ct*32 + g*8 + hi*4 + rr, q = wv*32 + l31
    // store layout: O_part[bid*8192 + (c>>2)*512 + q*4 + (c&3)]
    const size_t pbase = (size_t)bid * 8192;
    const int q = wv * 32 + l31;
#pragma unroll
    for (int ct = 0; ct < 2; ++ct)
#pragma unroll
        for (int g = 0; g < 4; ++g) {
            int w0, w1;
            asm("v_cvt_pk_bf16_f32 %0, %1, %2" : "=v"(w0) : "v"(o[ct][4 * g + 0]), "v"(o[ct][4 * g + 1]));
            asm("v_cvt_pk_bf16_f32 %0, %1, %2" : "=v"(w1) : "v"(o[ct][4 * g + 2]), "v"(o[ct][4 * g + 3]));
            uint2 pk2;
            pk2.x = (unsigned)w0;
            pk2.y = (unsigned)w1;
            *reinterpret_cast<uint2*>(
                &O_part[pbase + (size_t)(ct * 8 + g * 2 + hi) * 512 + q * 4]) = pk2;
        }
}

// ---------------------------------------------------------------- combine --
// grid 512: one 32-q slice per block (2 blocks/CU). ab = attn qi (128-q),
// sub = which 32-q quarter. LDS stride 65 -> conflict-free scalar access.
__global__ __launch_bounds__(256) void combine_kernel(
    const u16* __restrict__ O_part, const float* __restrict__ l_part,
    const float* __restrict__ x, const float* __restrict__ g_gamma,
    float* __restrict__ out)
{
    __shared__ float ot[32 * 65];   // [q-local][c]
    __shared__ float ls[32];
    const int t = threadIdx.x;
    const int ab = blockIdx.x >> 2;
    const int sub = blockIdx.x & 3;
    const int b = ab >> 5;
    const int n0 = (ab & 31) << 7;
    const float gamma = g_gamma[0];

#pragma unroll
    for (int i = 0; i < 2; ++i) {
        int idx = t + i * 256;
        int c4 = idx >> 5, ql = idx & 31;
        float a0 = 0.f, a1 = 0.f, a2 = 0.f, a3 = 0.f;
#pragma unroll
        for (int s4 = 0; s4 < NSPLIT; ++s4) {
            uint2 u = *reinterpret_cast<const uint2*>(
                O_part + ((size_t)(ab * NSPLIT + s4)) * 8192 +
                (size_t)c4 * 512 + (sub * 32 + ql) * 4);
            a0 += bf2f((u16)(u.x & 0xFFFF));
            a1 += bf2f((u16)(u.x >> 16));
            a2 += bf2f((u16)(u.y & 0xFFFF));
            a3 += bf2f((u16)(u.y >> 16));
        }
        ot[ql * 65 + c4 * 4 + 0] = a0;
        ot[ql * 65 + c4 * 4 + 1] = a1;
        ot[ql * 65 + c4 * 4 + 2] = a2;
        ot[ql * 65 + c4 * 4 + 3] = a3;
    }
    if (t < 32) {
        float lsum = 0.f;
#pragma unroll
        for (int s4 = 0; s4 < NSPLIT; ++s4)
            lsum += l_part[((size_t)(ab * NSPLIT + s4)) * 128 + sub * 32 + t];
        ls[t] = gamma / fmaxf(lsum, 1e-30f);
    }
    __syncthreads();
    {
        const int c = t >> 2, seg = t & 3;
        const size_t gbase = ((size_t)(b * 64 + c)) * 4096 + n0 + sub * 32 + seg * 8;
#pragma unroll
        for (int j = 0; j < 2; ++j) {
            float4 xv = *reinterpret_cast<const float4*>(&x[gbase + j * 4]);
            float4 rv;
            int nl = seg * 8 + j * 4;
            rv.x = ot[(nl + 0) * 65 + c] * ls[nl + 0] + xv.x;
            rv.y = ot[(nl + 1) * 65 + c] * ls[nl + 1] + xv.y;
            rv.z = ot[(nl + 2) * 65 + c] * ls[nl + 2] + xv.z;
            rv.w = ot[(nl + 3) * 65 + c] * ls[nl + 3] + xv.w;
            *reinterpret_cast<float4*>(&out[gbase + j * 4]) = rv;
        }
    }
}

// ---------------------------------------------------------------- launch ---
extern "C" void kernel_launch(void* const* d_in, const int* in_sizes, int n_in,
                              void* d_out, int out_size, void* d_ws, size_t ws_size,
                              hipStream_t stream) {
    const float* x      = (const float*)d_in[0];
    const float* Wq     = (const float*)d_in[1];
    const float* bq     = (const float*)d_in[2];
    const float* Wk     = (const float*)d_in[3];
    const float* bk     = (const float*)d_in[4];
    const float* Wv     = (const float*)d_in[5];
    const float* bv     = (const float*)d_in[6];
    const float* We1    = (const float*)d_in[7];
    const float* be1    = (const float*)d_in[8];
    const float* bn_w   = (const float*)d_in[9];
    const float* bn_b   = (const float*)d_in[10];
    const float* bn_mean= (const float*)d_in[11];
    const float* bn_var = (const float*)d_in[12];
    const float* We2    = (const float*)d_in[13];
    const float* be2    = (const float*)d_in[14];
    const float* gamma  = (const float*)d_in[15];
    const float* beta   = (const float*)d_in[16];

    char* ws = (char*)d_ws;
    const size_t MB = 1024 * 1024;
    u16*   Qt     = (u16*)ws;                // [0, 2 MB)
    u16*   Kt     = (u16*)(ws + 2 * MB);     // [2, 4.625 MB) 4 x 327680 u16
    u16*   Vm     = (u16*)(ws + 5 * MB);     // [5, 7 MB)
    float* l_part = (float*)(ws + 7 * MB);   // 512 KB (1024 blk x 128)
    u16*   O_part = (u16*)(ws + 8 * MB);     // 16.78 MB (1024 x 8192)

    float* out = (float*)d_out;

    qkv_edge_kernel<<<dim3(512), dim3(256), 0, stream>>>(
        x, Wq, bq, Wk, bk, Wv, bv, We1, be1, bn_w, bn_b, bn_mean, bn_var,
        We2, be2, beta, Qt, Kt, Vm);
    attn_kernel<<<dim3(128 * NSPLIT), dim3(256), 0, stream>>>(
        Qt, Kt, Vm, O_part, l_part);
    combine_kernel<<<dim3(512), dim3(256), 0, stream>>>(
        O_part, l_part, x, gamma, out);
}

// Round 7
// 162.681 us; speedup vs baseline: 1.0708x; 1.0297x over previous
//
#include <hip/hip_runtime.h>
#include <hip/hip_bf16.h>

typedef unsigned short u16;
typedef __attribute__((ext_vector_type(8))) __bf16 bf16x8;
typedef __attribute__((ext_vector_type(4))) float f32x4;
typedef __attribute__((ext_vector_type(16))) float f32x16;

// Fragment-chunk layout for Qt/Vm (per batch, 4096x64 u16):
//   element (row n, channel c) -> ((n>>4)*8 + (c>>3))*128 + (n&15)*8 + (c&7)
//   (Vm stores V^T: "row" = channel, "col" = key.)
// Kt: TILE-MAJOR, stride 5120 u16 per 64-key tile: first 4096 = fragment-
//   chunk layout; last 1024 = "5th chunk" (ch64 = lw' = log2(1+beta*sig),
//   ch65 = 1.0). Q-side pairs it with constant frag {1.0, -17.25} so
//   s = K.q + lw' - 17.25 comes out of the MFMA; p = exp2(s); offset
//   cancels in the L1 renorm.
// attn r20 = r19 with the PV INTERLEAVED per 32-key half-tile.
//   r19 post-mortem: VGPR_Count=64 = the arch half of a 64+64 arch/AGPR
//   split of the (256,4) 128-reg cap; softmax state (~100 arch regs with
//   both half-tiles' s/p/pbu live) overflowed the arch half -> 184MB scratch
//   WRITE. Occupancy ladder worked (22->39%, 78->66us despite spill), so
//   keep (256,4) and halve the live state: per tl do QK -> exp2 -> pack ->
//   PV immediately (V chunks tl*2, tl*2+1). Peak ~110 total / ~78 arch.
// r9 lesson: cross-block combine via threadfence+counter FAILED on HW
// (stale cross-XCD partials) - combine stays a separate kernel.
// r13/r15 ledger: total = ~43us ws-poison fill (fixed) + attn + ~61us
//   residual. attn history: r14 53 -> r15/r17 ~33 (reg) -> r18 78 (spill)
//   -> r19 66 (spill, higher occ). Fallback if WRITE>40MB: revert to r17.

#define NSPLIT 8

__device__ __forceinline__ u16 f2bf(float f) {
    unsigned u = __builtin_bit_cast(unsigned, f);
    u += 0x7FFFu + ((u >> 16) & 1u);
    return (u16)(u >> 16);
}
__device__ __forceinline__ float bf2f(u16 v) {
    unsigned u = ((unsigned)v) << 16;
    return __builtin_bit_cast(float, u);
}
__device__ __forceinline__ void gl_lds16(const u16* g, u16* l) {
    __builtin_amdgcn_global_load_lds(
        (const __attribute__((address_space(1))) unsigned*)g,
        (__attribute__((address_space(3))) unsigned*)l, 16, 0, 0);
}

// ------------------------------------------------------------ qkv + edge ---
__global__ __launch_bounds__(256) void qkv_edge_kernel(
    const float* __restrict__ x,
    const float* __restrict__ Wq, const float* __restrict__ bq,
    const float* __restrict__ Wk, const float* __restrict__ bk,
    const float* __restrict__ Wv, const float* __restrict__ bv,
    const float* __restrict__ We1, const float* __restrict__ be1,
    const float* __restrict__ bn_w, const float* __restrict__ bn_b,
    const float* __restrict__ bn_mean, const float* __restrict__ bn_var,
    const float* __restrict__ We2, const float* __restrict__ be2,
    const float* __restrict__ beta,
    u16* __restrict__ Qt, u16* __restrict__ Kt, u16* __restrict__ Vm)
{
    __shared__ __align__(16) u16 sm[33280];
    const int t = threadIdx.x;
    const int wv = t >> 6, lane = t & 63;
    const int quad = lane >> 4, l15 = lane & 15;

    if (blockIdx.x < 256) {
        // ---------------- qkv ----------------
        u16* Wl   = sm;                 // [3][64][72]
        u16* xt_s = sm + 13824;         // [64][66]
        u16* vt   = sm + 13824 + 4224;  // [64][72]
        const int b = blockIdx.x >> 6;
        const int n0 = (blockIdx.x & 63) << 6;

        const float* Wmat[3] = {Wq, Wk, Wv};
#pragma unroll
        for (int m = 0; m < 3; ++m)
#pragma unroll
            for (int i = 0; i < 4; ++i) {
                int u = t + i * 256;
                float4 w4 = *reinterpret_cast<const float4*>(Wmat[m] + u * 4);
                int row = u >> 4, col = (u & 15) * 4;
                uint2 pk;
                pk.x = (unsigned)f2bf(w4.x) | ((unsigned)f2bf(w4.y) << 16);
                pk.y = (unsigned)f2bf(w4.z) | ((unsigned)f2bf(w4.w) << 16);
                *reinterpret_cast<uint2*>(&Wl[(m * 64 + row) * 72 + col]) = pk;
            }
        for (int i = 0; i < 16; ++i) {
            int lin = t + i * 256;
            int c = lin >> 6, nn = lin & 63;
            xt_s[nn * 66 + c] = f2bf(x[(size_t)(b * 64 + c) * 4096 + n0 + nn]);
        }
        __syncthreads();

        bf16x8 bx[2];
#pragma unroll
        for (int h = 0; h < 2; ++h)
            bx[h] = *reinterpret_cast<const bf16x8*>(
                &xt_s[(wv * 16 + l15) * 66 + h * 32 + quad * 8]);

        f32x4 d[3][4];
#pragma unroll
        for (int m = 0; m < 3; ++m)
#pragma unroll
            for (int mt = 0; mt < 4; ++mt) d[m][mt] = (f32x4){0.f, 0.f, 0.f, 0.f};

#pragma unroll
        for (int h = 0; h < 2; ++h)
#pragma unroll
            for (int m = 0; m < 3; ++m)
#pragma unroll
                for (int mt = 0; mt < 4; ++mt) {
                    bf16x8 af = *reinterpret_cast<const bf16x8*>(
                        &Wl[(m * 64 + mt * 16 + l15) * 72 + h * 32 + quad * 8]);
                    d[m][mt] = __builtin_amdgcn_mfma_f32_16x16x32_bf16(af, bx[h], d[m][mt], 0, 0, 0);
                }

        const float* bias[3] = {bq, bk, bv};
        const float L2E = 1.44269504f;
#pragma unroll
        for (int m = 0; m < 3; ++m)
#pragma unroll
            for (int mt = 0; mt < 4; ++mt) {
                float4 bi = *reinterpret_cast<const float4*>(bias[m] + mt * 16 + quad * 4);
                d[m][mt][0] += bi.x; d[m][mt][1] += bi.y; d[m][mt][2] += bi.z; d[m][mt][3] += bi.w;
                if (m == 0) {
                    d[m][mt][0] *= L2E; d[m][mt][1] *= L2E;
                    d[m][mt][2] *= L2E; d[m][mt][3] *= L2E;
                }
            }

        // Q store: old global fragment-chunk layout
        const int rowchunk = (n0 >> 4) + wv;
        {
            u16* baseQ = Qt + (size_t)b * 262144;
#pragma unroll
            for (int mt = 0; mt < 4; ++mt) {
                uint2 pk;
                pk.x = (unsigned)f2bf(d[0][mt][0]) | ((unsigned)f2bf(d[0][mt][1]) << 16);
                pk.y = (unsigned)f2bf(d[0][mt][2]) | ((unsigned)f2bf(d[0][mt][3]) << 16);
                *reinterpret_cast<uint2*>(
                    baseQ + ((size_t)(rowchunk * 8 + mt * 2 + (quad >> 1))) * 128 +
                    l15 * 8 + (quad & 1) * 4) = pk;
            }
        }
        // K store: tile-major, stride 5120; within-tile chunk = wv*8 + c>>3
        {
            u16* baseK = Kt + (size_t)b * 327680 + (size_t)(n0 >> 6) * 5120;
#pragma unroll
            for (int mt = 0; mt < 4; ++mt) {
                uint2 pk;
                pk.x = (unsigned)f2bf(d[1][mt][0]) | ((unsigned)f2bf(d[1][mt][1]) << 16);
                pk.y = (unsigned)f2bf(d[1][mt][2]) | ((unsigned)f2bf(d[1][mt][3]) << 16);
                *reinterpret_cast<uint2*>(
                    baseK + (size_t)(wv * 8 + mt * 2 + (quad >> 1)) * 128 +
                    l15 * 8 + (quad & 1) * 4) = pk;
            }
        }
#pragma unroll
        for (int mt = 0; mt < 4; ++mt)
#pragma unroll
            for (int r = 0; r < 4; ++r)
                vt[(mt * 16 + quad * 4 + r) * 72 + wv * 16 + l15] = f2bf(d[2][mt][r]);
        __syncthreads();
        {
            u16* Vb_st = Vm + (size_t)b * 262144;
            const int kt = n0 >> 6;
#pragma unroll
            for (int i = 0; i < 2; ++i) {
                int unit = t + i * 256;
                int f = unit >> 7, hq = (unit >> 4) & 7, cl = unit & 15;
                const u16* src = &vt[(f * 16 + cl) * 72 + hq * 8];
                uint4 v4 = *reinterpret_cast<const uint4*>(src);
                *reinterpret_cast<uint4*>(
                    Vb_st + ((size_t)((kt * 4 + f) * 8 + hq)) * 128 + cl * 8) = v4;
            }
        }
    } else {
        // ---------------- edge ----------------
        u16* Ae_s = sm;            // [32][584]
        u16* xr_s = sm + 18688;    // [3][66][72]
        const int eb = blockIdx.x - 256;
        const int b = eb >> 6, h = eb & 63;

        if (t < 192) {
            int kh = t / 64, rem = t & 63;
            int col = (rem >> 5) * 65, ci2 = (rem & 31) * 2;
            *reinterpret_cast<unsigned*>(&xr_s[(kh * 66 + col) * 72 + ci2]) = 0u;
        }
#pragma unroll
        for (int i = 0; i < 18; ++i) {
            int u = t + i * 256;
            int ch = u / 144;
            int rem = u - ch * 144;
            int p = rem >> 4, cig = (rem & 15) * 4;
            const float* src = We1 + ch * 576 + cig * 9 + p;
            float a = src[0], b2 = src[9], c2 = src[18], d2 = src[27];
            uint2 pk;
            pk.x = (unsigned)f2bf(a) | ((unsigned)f2bf(b2) << 16);
            pk.y = (unsigned)f2bf(c2) | ((unsigned)f2bf(d2) << 16);
            *reinterpret_cast<uint2*>(&Ae_s[ch * 584 + p * 64 + cig]) = pk;
        }
#pragma unroll
        for (int i = 0; i < 12; ++i) {
            int u = t + i * 256;
            int w = u & 63, cig = (u >> 6) & 15, kh = u >> 10;
            int hs = h + kh - 1;
            float v0 = 0.f, v1 = 0.f, v2 = 0.f, v3 = 0.f;
            if ((unsigned)hs < 64u) {
                const float* src = x + ((size_t)(b * 64 + cig * 4) * 64 + hs) * 64 + w;
                v0 = src[0]; v1 = src[4096]; v2 = src[8192]; v3 = src[12288];
            }
            uint2 pk;
            pk.x = (unsigned)f2bf(v0) | ((unsigned)f2bf(v1) << 16);
            pk.y = (unsigned)f2bf(v2) | ((unsigned)f2bf(v3) << 16);
            *reinterpret_cast<uint2*>(&xr_s[(kh * 66 + w + 1) * 72 + cig * 4]) = pk;
        }
        __syncthreads();

        f32x4 e[2];
        e[0] = (f32x4){0.f, 0.f, 0.f, 0.f};
        e[1] = (f32x4){0.f, 0.f, 0.f, 0.f};
#pragma unroll
        for (int p = 0; p < 9; ++p) {
            const int kh = p / 3, kw = p - kh * 3;
#pragma unroll
            for (int half = 0; half < 2; ++half) {
                bf16x8 bfr = *reinterpret_cast<const bf16x8*>(
                    &xr_s[(kh * 66 + wv * 16 + l15 + kw) * 72 + half * 32 + quad * 8]);
#pragma unroll
                for (int mt = 0; mt < 2; ++mt) {
                    bf16x8 af = *reinterpret_cast<const bf16x8*>(
                        &Ae_s[(mt * 16 + l15) * 584 + p * 64 + half * 32 + quad * 8]);
                    e[mt] = __builtin_amdgcn_mfma_f32_16x16x32_bf16(af, bfr, e[mt], 0, 0, 0);
                }
            }
        }
        float partial = 0.f;
#pragma unroll
        for (int mt = 0; mt < 2; ++mt) {
            float4 bw = *reinterpret_cast<const float4*>(bn_w    + mt * 16 + quad * 4);
            float4 bb = *reinterpret_cast<const float4*>(bn_b    + mt * 16 + quad * 4);
            float4 bm = *reinterpret_cast<const float4*>(bn_mean + mt * 16 + quad * 4);
            float4 bv2 = *reinterpret_cast<const float4*>(bn_var + mt * 16 + quad * 4);
            float4 b1 = *reinterpret_cast<const float4*>(be1     + mt * 16 + quad * 4);
            float4 w2 = *reinterpret_cast<const float4*>(We2     + mt * 16 + quad * 4);
            float sc, sh;
            sc = bw.x * rsqrtf(bv2.x + 1e-5f); sh = (b1.x - bm.x) * sc + bb.x;
            partial += fmaxf(e[mt][0] * sc + sh, 0.f) * w2.x;
            sc = bw.y * rsqrtf(bv2.y + 1e-5f); sh = (b1.y - bm.y) * sc + bb.y;
            partial += fmaxf(e[mt][1] * sc + sh, 0.f) * w2.y;
            sc = bw.z * rsqrtf(bv2.z + 1e-5f); sh = (b1.z - bm.z) * sc + bb.z;
            partial += fmaxf(e[mt][2] * sc + sh, 0.f) * w2.z;
            sc = bw.w * rsqrtf(bv2.w + 1e-5f); sh = (b1.w - bm.w) * sc + bb.w;
            partial += fmaxf(e[mt][3] * sc + sh, 0.f) * w2.w;
        }
        partial += __shfl_xor(partial, 16);
        partial += __shfl_xor(partial, 32);
        if (lane < 16) {
            float s = partial + be2[0];
            float sg = 1.f / (1.f + __expf(-s));
            // 5th-chunk write: ch64 = lw' = log2(1+beta*sig), ch65 = 1.0.
            float lwp = __log2f(fmaxf(1.f + beta[0] * sg, 1e-20f));
            u16* k5 = Kt + (size_t)b * 327680 + (size_t)h * 5120 + 4096 +
                      (wv >> 1) * 512 + (wv & 1) * 256 + lane * 8;
            uint4 st0;
            st0.x = (unsigned)f2bf(lwp) | 0x3F800000u;  // {lw', 1.0}
            st0.y = 0u; st0.z = 0u; st0.w = 0u;
            *reinterpret_cast<uint4*>(k5) = st0;
            uint4 z; z.x = 0u; z.y = 0u; z.z = 0u; z.w = 0u;
            *reinterpret_cast<uint4*>(k5 + 128) = z;   // hi=1 half: zeros
        }
    }
}

// ------------------------------------------------------------- attention ---
// grid 128*NSPLIT(=1024); 256 thr = 4 waves x 32 q rows (QBLK=128), 8 kt-iters
// of 64 keys. 32x32x16 MFMA; swapped QK^T; P->B-frag via cvt_pk+permlane32.
// r20: double-buffered LDS staging (global_load_lds w=16; waves 0-1 K, 2-3 V)
// + per-half-tile interleaved [QK -> exp2 -> pack -> PV] so only ONE tl's
// softmax state is live (r19's both-halves-live overflowed the 64-arch half
// of the 128-reg (256,4) split -> scratch). One __syncthreads per iter.
__global__ __launch_bounds__(256, 4) void attn_kernel(
    const u16* __restrict__ Qt, const u16* __restrict__ Kt,
    const u16* __restrict__ Vm,
    u16* __restrict__ O_part, float* __restrict__ l_part)
{
    constexpr int KT_ITERS = 64 / NSPLIT;   // 8
    __shared__ __align__(16) u16 kv[2][9216];   // [buf][ K 5120 | V 4096 ]

    // bijective XCD swizzle: 1024 blocks, 8 XCDs -> contiguous 128-block chunks
    const int bid = ((blockIdx.x & 7) << 7) + (blockIdx.x >> 3);
    const int t = threadIdx.x;
    const int qi = bid / NSPLIT;            // 0..127: (b, 128-q group)
    const int split = bid % NSPLIT;
    const int b = qi >> 5;
    const int n0 = (qi & 31) << 7;
    const int wv = t >> 6, lane = t & 63;
    const int l31 = lane & 31, hi = lane >> 5;
    const int i4 = (lane >> 4) & 1, l15 = lane & 15;

    const int kvoff = i4 * 1024 + hi * 128 + l15 * 8;   // within 4096-elem tile
    const int k5off = i4 * 256 + hi * 128 + l15 * 8;    // within 1024-elem chunk
    const u16* Qb  = Qt + (size_t)b * 262144;
    const u16* Ksp = Kt + (size_t)b * 327680 + (size_t)(split * KT_ITERS) * 5120;
    const u16* Vsp = Vm + (size_t)b * 262144 + (size_t)(split * KT_ITERS) * 4096;

    // Q B-frags: col=q=n0+wv*32+l31, k-chunk kc
    bf16x8 qf[4];
#pragma unroll
    for (int kc = 0; kc < 4; ++kc)
        qf[kc] = __builtin_bit_cast(bf16x8, *reinterpret_cast<const uint4*>(
            Qb + (size_t)(((n0 >> 4) + wv * 2) * 1024) + kvoff + kc * 256));
    // constant Q frag for the lw chunk: ch64 = 1.0, ch65 = -17.25 (bf16-exact)
    uint4 qc5u;
    qc5u.x = hi ? 0u : 0xC18A3F80u;
    qc5u.y = 0u; qc5u.z = 0u; qc5u.w = 0u;
    const bf16x8 qc5 = __builtin_bit_cast(bf16x8, qc5u);

    // stage tile `tile` (0..7) into buffer buf: waves 0-1 K (640 x 16B units),
    // waves 2-3 V (512 units). LDS dest linear in lane (global_load_lds rule).
    auto STAGE = [&](int buf, int tile) {
        if (wv < 2) {
            const u16* Kg = Ksp + (size_t)tile * 5120 + (wv * 320 + lane) * 8;
            u16* Kl = &kv[buf][(wv * 320 + lane) * 8];
#pragma unroll
            for (int i = 0; i < 5; ++i)
                gl_lds16(Kg + i * 512, Kl + i * 512);
        } else {
            const u16* Vg = Vsp + (size_t)tile * 4096 + ((wv - 2) * 256 + lane) * 8;
            u16* Vl = &kv[buf][5120 + ((wv - 2) * 256 + lane) * 8];
#pragma unroll
            for (int i = 0; i < 4; ++i)
                gl_lds16(Vg + i * 512, Vl + i * 512);
        }
    };

    f32x16 o[2];      // [c-tile of 32]: O^T[c][q]
#pragma unroll
    for (int ct = 0; ct < 2; ++ct)
#pragma unroll
        for (int i = 0; i < 16; ++i) o[ct][i] = 0.f;
    float lacc = 0.f;

    STAGE(0, 0);
    __syncthreads();    // implicit vmcnt(0): tile 0 resident

    int cur = 0;
    for (int kt = 0; kt < KT_ITERS; ++kt) {
        if (kt + 1 < KT_ITERS) STAGE(cur ^ 1, kt + 1);

        const u16* Kl = &kv[cur][0];
        const u16* Vl = &kv[cur][5120];

        // per 32-key half-tile: QK^T -> exp2 -> pack -> PV (state live for
        // one tl only). s = K.q + lw' - 17.25 via the 5th chunk.
#pragma unroll
        for (int tl = 0; tl < 2; ++tl) {
            bf16x8 k4 = *reinterpret_cast<const bf16x8*>(Kl + 4096 + tl * 512 + k5off);
            bf16x8 k0 = *reinterpret_cast<const bf16x8*>(Kl + tl * 2048 + kvoff);
            bf16x8 k1 = *reinterpret_cast<const bf16x8*>(Kl + tl * 2048 + 256 + kvoff);
            bf16x8 k2 = *reinterpret_cast<const bf16x8*>(Kl + tl * 2048 + 512 + kvoff);
            bf16x8 k3 = *reinterpret_cast<const bf16x8*>(Kl + tl * 2048 + 768 + kvoff);
            f32x16 s;
#pragma unroll
            for (int i = 0; i < 16; ++i) s[i] = 0.f;
            __builtin_amdgcn_s_setprio(1);
            s = __builtin_amdgcn_mfma_f32_32x32x16_bf16(k4, qc5,   s, 0, 0, 0);
            s = __builtin_amdgcn_mfma_f32_32x32x16_bf16(k0, qf[0], s, 0, 0, 0);
            s = __builtin_amdgcn_mfma_f32_32x32x16_bf16(k1, qf[1], s, 0, 0, 0);
            s = __builtin_amdgcn_mfma_f32_32x32x16_bf16(k2, qf[2], s, 0, 0, 0);
            s = __builtin_amdgcn_mfma_f32_32x32x16_bf16(k3, qf[3], s, 0, 0, 0);
            __builtin_amdgcn_s_setprio(0);

            float p[16];
#pragma unroll
            for (int i = 0; i < 16; ++i) p[i] = exp2f(s[i]);
            float t0 = (p[0] + p[1]) + (p[2] + p[3]);
            float t1 = (p[4] + p[5]) + (p[6] + p[7]);
            float t2 = (p[8] + p[9]) + (p[10] + p[11]);
            float t3 = (p[12] + p[13]) + (p[14] + p[15]);
            lacc += (t0 + t1) + (t2 + t3);

            uint4 pb[2];
#pragma unroll
            for (int kc2 = 0; kc2 < 2; ++kc2) {
                int a0, a1, b0, b1;
                asm("v_cvt_pk_bf16_f32 %0, %1, %2" : "=v"(a0) : "v"(p[kc2 * 8 + 0]), "v"(p[kc2 * 8 + 1]));
                asm("v_cvt_pk_bf16_f32 %0, %1, %2" : "=v"(a1) : "v"(p[kc2 * 8 + 2]), "v"(p[kc2 * 8 + 3]));
                asm("v_cvt_pk_bf16_f32 %0, %1, %2" : "=v"(b0) : "v"(p[kc2 * 8 + 4]), "v"(p[kc2 * 8 + 5]));
                asm("v_cvt_pk_bf16_f32 %0, %1, %2" : "=v"(b1) : "v"(p[kc2 * 8 + 6]), "v"(p[kc2 * 8 + 7]));
                auto swA = __builtin_amdgcn_permlane32_swap(a0, b0, false, false);
                auto swB = __builtin_amdgcn_permlane32_swap(a1, b1, false, false);
                uint4 fr;
                fr.x = (unsigned)swA[0];   // keys hi*8 + 0,1
                fr.y = (unsigned)swB[0];   // keys hi*8 + 2,3
                fr.z = (unsigned)swA[1];   // keys hi*8 + 4,5
                fr.w = (unsigned)swB[1];   // keys hi*8 + 6,7
                pb[kc2] = fr;
            }

            // PV for this half-tile: key chunks tl*2+kc2
            __builtin_amdgcn_s_setprio(1);
#pragma unroll
            for (int ct = 0; ct < 2; ++ct) {
                bf16x8 va = *reinterpret_cast<const bf16x8*>(
                    Vl + ct * 2048 + (tl * 2 + 0) * 256 + kvoff);
                bf16x8 vb = *reinterpret_cast<const bf16x8*>(
                    Vl + ct * 2048 + (tl * 2 + 1) * 256 + kvoff);
                o[ct] = __builtin_amdgcn_mfma_f32_32x32x16_bf16(va,
                            __builtin_bit_cast(bf16x8, pb[0]), o[ct], 0, 0, 0);
                o[ct] = __builtin_amdgcn_mfma_f32_32x32x16_bf16(vb,
                            __builtin_bit_cast(bf16x8, pb[1]), o[ct], 0, 0, 0);
            }
            __builtin_amdgcn_s_setprio(0);
        }

        __syncthreads();   // stage(next) drained + all waves done with cur
        cur ^= 1;
    }

    // l: lane (hi,q) holds half the keys' sum; combine halves via shfl_xor(32)
    float ltot = lacc + __shfl_xor(lacc, 32);
    if (lane < 32)
        l_part[(size_t)bid * 128 + wv * 32 + lane] = ltot;

    // O^T[c][q]: c = ct*32 + g*8 + hi*4 + rr, q = wv*32 + l31
    // store layout: O_part[bid*8192 + (c>>2)*512 + q*4 + (c&3)]
    const size_t pbase = (size_t)bid * 8192;
    const int q = wv * 32 + l31;
#pragma unroll
    for (int ct = 0; ct < 2; ++ct)
#pragma unroll
        for (int g = 0; g < 4; ++g) {
            int w0, w1;
            asm("v_cvt_pk_bf16_f32 %0, %1, %2" : "=v"(w0) : "v"(o[ct][4 * g + 0]), "v"(o[ct][4 * g + 1]));
            asm("v_cvt_pk_bf16_f32 %0, %1, %2" : "=v"(w1) : "v"(o[ct][4 * g + 2]), "v"(o[ct][4 * g + 3]));
            uint2 pk2;
            pk2.x = (unsigned)w0;
            pk2.y = (unsigned)w1;
            *reinterpret_cast<uint2*>(
                &O_part[pbase + (size_t)(ct * 8 + g * 2 + hi) * 512 + q * 4]) = pk2;
        }
}

// ---------------------------------------------------------------- combine --
// grid 512: one 32-q slice per block (2 blocks/CU). ab = attn qi (128-q),
// sub = which 32-q quarter. LDS stride 65 -> conflict-free scalar access.
__global__ __launch_bounds__(256) void combine_kernel(
    const u16* __restrict__ O_part, const float* __restrict__ l_part,
    const float* __restrict__ x, const float* __restrict__ g_gamma,
    float* __restrict__ out)
{
    __shared__ float ot[32 * 65];   // [q-local][c]
    __shared__ float ls[32];
    const int t = threadIdx.x;
    const int ab = blockIdx.x >> 2;
    const int sub = blockIdx.x & 3;
    const int b = ab >> 5;
    const int n0 = (ab & 31) << 7;
    const float gamma = g_gamma[0];

#pragma unroll
    for (int i = 0; i < 2; ++i) {
        int idx = t + i * 256;
        int c4 = idx >> 5, ql = idx & 31;
        float a0 = 0.f, a1 = 0.f, a2 = 0.f, a3 = 0.f;
#pragma unroll
        for (int s4 = 0; s4 < NSPLIT; ++s4) {
            uint2 u = *reinterpret_cast<const uint2*>(
                O_part + ((size_t)(ab * NSPLIT + s4)) * 8192 +
                (size_t)c4 * 512 + (sub * 32 + ql) * 4);
            a0 += bf2f((u16)(u.x & 0xFFFF));
            a1 += bf2f((u16)(u.x >> 16));
            a2 += bf2f((u16)(u.y & 0xFFFF));
            a3 += bf2f((u16)(u.y >> 16));
        }
        ot[ql * 65 + c4 * 4 + 0] = a0;
        ot[ql * 65 + c4 * 4 + 1] = a1;
        ot[ql * 65 + c4 * 4 + 2] = a2;
        ot[ql * 65 + c4 * 4 + 3] = a3;
    }
    if (t < 32) {
        float lsum = 0.f;
#pragma unroll
        for (int s4 = 0; s4 < NSPLIT; ++s4)
            lsum += l_part[((size_t)(ab * NSPLIT + s4)) * 128 + sub * 32 + t];
        ls[t] = gamma / fmaxf(lsum, 1e-30f);
    }
    __syncthreads();
    {
        const int c = t >> 2, seg = t & 3;
        const size_t gbase = ((size_t)(b * 64 + c)) * 4096 + n0 + sub * 32 + seg * 8;
#pragma unroll
        for (int j = 0; j < 2; ++j) {
            float4 xv = *reinterpret_cast<const float4*>(&x[gbase + j * 4]);
            float4 rv;
            int nl = seg * 8 + j * 4;
            rv.x = ot[(nl + 0) * 65 + c] * ls[nl + 0] + xv.x;
            rv.y = ot[(nl + 1) * 65 + c] * ls[nl + 1] + xv.y;
            rv.z = ot[(nl + 2) * 65 + c] * ls[nl + 2] + xv.z;
            rv.w = ot[(nl + 3) * 65 + c] * ls[nl + 3] + xv.w;
            *reinterpret_cast<float4*>(&out[gbase + j * 4]) = rv;
        }
    }
}

// ---------------------------------------------------------------- launch ---
extern "C" void kernel_launch(void* const* d_in, const int* in_sizes, int n_in,
                              void* d_out, int out_size, void* d_ws, size_t ws_size,
                              hipStream_t stream) {
    const float* x      = (const float*)d_in[0];
    const float* Wq     = (const float*)d_in[1];
    const float* bq     = (const float*)d_in[2];
    const float* Wk     = (const float*)d_in[3];
    const float* bk     = (const float*)d_in[4];
    const float* Wv     = (const float*)d_in[5];
    const float* bv     = (const float*)d_in[6];
    const float* We1    = (const float*)d_in[7];
    const float* be1    = (const float*)d_in[8];
    const float* bn_w   = (const float*)d_in[9];
    const float* bn_b   = (const float*)d_in[10];
    const float* bn_mean= (const float*)d_in[11];
    const float* bn_var = (const float*)d_in[12];
    const float* We2    = (const float*)d_in[13];
    const float* be2    = (const float*)d_in[14];
    const float* gamma  = (const float*)d_in[15];
    const float* beta   = (const float*)d_in[16];

    char* ws = (char*)d_ws;
    const size_t MB = 1024 * 1024;
    u16*   Qt     = (u16*)ws;                // [0, 2 MB)
    u16*   Kt     = (u16*)(ws + 2 * MB);     // [2, 4.625 MB) 4 x 327680 u16
    u16*   Vm     = (u16*)(ws + 5 * MB);     // [5, 7 MB)
    float* l_part = (float*)(ws + 7 * MB);   // 512 KB (1024 blk x 128)
    u16*   O_part = (u16*)(ws + 8 * MB);     // 16.78 MB (1024 x 8192)

    float* out = (float*)d_out;

    qkv_edge_kernel<<<dim3(512), dim3(256), 0, stream>>>(
        x, Wq, bq, Wk, bk, Wv, bv, We1, be1, bn_w, bn_b, bn_mean, bn_var,
        We2, be2, beta, Qt, Kt, Vm);
    attn_kernel<<<dim3(128 * NSPLIT), dim3(256), 0, stream>>>(
        Qt, Kt, Vm, O_part, l_part);
    combine_kernel<<<dim3(512), dim3(256), 0, stream>>>(
        O_part, l_part, x, gamma, out);
}

// Round 8
// 133.517 us; speedup vs baseline: 1.3047x; 1.2184x over previous
//
#include <hip/hip_runtime.h>
#include <hip/hip_bf16.h>

typedef unsigned short u16;
typedef __attribute__((ext_vector_type(8))) __bf16 bf16x8;
typedef __attribute__((ext_vector_type(4))) float f32x4;
typedef __attribute__((ext_vector_type(16))) float f32x16;

// Fragment-chunk layout for Qt/Vm (per batch, 4096x64 u16):
//   element (row n, channel c) -> ((n>>4)*8 + (c>>3))*128 + (n&15)*8 + (c&7)
//   (Vm stores V^T: "row" = channel, "col" = key.)
// Kt: TILE-MAJOR, stride 5120 u16 per 64-key tile: first 4096 = fragment-
//   chunk layout; last 1024 = "5th chunk" (ch64 = lw' = log2(1+beta*sig),
//   ch65 = 1.0). Q-side pairs it with constant frag {1.0, -17.25} so
//   s = K.q + lw' - 17.25 comes out of the MFMA; p = exp2(s); offset
//   cancels in the L1 renorm.
// attn r21 = r20 with softmax processed in 8-ELEMENT HALVES.
//   r19/r20 post-mortem: VGPR_Count pinned at 64 both rounds = the arch half
//   of the (256,4) 128-reg budget (accum_offset=64; o+s live in the AGPR
//   half). The ARCH half must hold qf(16)+Kfrags(20)+p(16)+pb(8)+addr -> ~68
//   > 64 -> ~9 f32/half-tile spilled = the 151-168MB scratch WRITE. Fix:
//   per-kc2 softmax (8 p live, s stays AGPR-resident): arch peak ~46 QK /
//   ~42 softmax / ~42 PV, all under 64. AGPR: o32+s16=48<=64.
//   PRE-COMMIT: if WRITE still >40MB, LDS path is dead -> revert to r17.
// r9 lesson: cross-block combine via threadfence+counter FAILED on HW
// (stale cross-XCD partials) - combine stays a separate kernel.
// r13/r15 ledger: total = ~43us ws-poison fill (fixed) + attn + ~61us
//   residual. attn history: r14 53 -> r15/r17 ~33 (reg) -> r18 78 (spill)
//   -> r19 66 -> r20 63 (spill persists). Best verified total: r17 @ 136.0.

#define NSPLIT 8

__device__ __forceinline__ u16 f2bf(float f) {
    unsigned u = __builtin_bit_cast(unsigned, f);
    u += 0x7FFFu + ((u >> 16) & 1u);
    return (u16)(u >> 16);
}
__device__ __forceinline__ float bf2f(u16 v) {
    unsigned u = ((unsigned)v) << 16;
    return __builtin_bit_cast(float, u);
}
__device__ __forceinline__ void gl_lds16(const u16* g, u16* l) {
    __builtin_amdgcn_global_load_lds(
        (const __attribute__((address_space(1))) unsigned*)g,
        (__attribute__((address_space(3))) unsigned*)l, 16, 0, 0);
}

// ------------------------------------------------------------ qkv + edge ---
__global__ __launch_bounds__(256) void qkv_edge_kernel(
    const float* __restrict__ x,
    const float* __restrict__ Wq, const float* __restrict__ bq,
    const float* __restrict__ Wk, const float* __restrict__ bk,
    const float* __restrict__ Wv, const float* __restrict__ bv,
    const float* __restrict__ We1, const float* __restrict__ be1,
    const float* __restrict__ bn_w, const float* __restrict__ bn_b,
    const float* __restrict__ bn_mean, const float* __restrict__ bn_var,
    const float* __restrict__ We2, const float* __restrict__ be2,
    const float* __restrict__ beta,
    u16* __restrict__ Qt, u16* __restrict__ Kt, u16* __restrict__ Vm)
{
    __shared__ __align__(16) u16 sm[33280];
    const int t = threadIdx.x;
    const int wv = t >> 6, lane = t & 63;
    const int quad = lane >> 4, l15 = lane & 15;

    if (blockIdx.x < 256) {
        // ---------------- qkv ----------------
        u16* Wl   = sm;                 // [3][64][72]
        u16* xt_s = sm + 13824;         // [64][66]
        u16* vt   = sm + 13824 + 4224;  // [64][72]
        const int b = blockIdx.x >> 6;
        const int n0 = (blockIdx.x & 63) << 6;

        const float* Wmat[3] = {Wq, Wk, Wv};
#pragma unroll
        for (int m = 0; m < 3; ++m)
#pragma unroll
            for (int i = 0; i < 4; ++i) {
                int u = t + i * 256;
                float4 w4 = *reinterpret_cast<const float4*>(Wmat[m] + u * 4);
                int row = u >> 4, col = (u & 15) * 4;
                uint2 pk;
                pk.x = (unsigned)f2bf(w4.x) | ((unsigned)f2bf(w4.y) << 16);
                pk.y = (unsigned)f2bf(w4.z) | ((unsigned)f2bf(w4.w) << 16);
                *reinterpret_cast<uint2*>(&Wl[(m * 64 + row) * 72 + col]) = pk;
            }
        for (int i = 0; i < 16; ++i) {
            int lin = t + i * 256;
            int c = lin >> 6, nn = lin & 63;
            xt_s[nn * 66 + c] = f2bf(x[(size_t)(b * 64 + c) * 4096 + n0 + nn]);
        }
        __syncthreads();

        bf16x8 bx[2];
#pragma unroll
        for (int h = 0; h < 2; ++h)
            bx[h] = *reinterpret_cast<const bf16x8*>(
                &xt_s[(wv * 16 + l15) * 66 + h * 32 + quad * 8]);

        f32x4 d[3][4];
#pragma unroll
        for (int m = 0; m < 3; ++m)
#pragma unroll
            for (int mt = 0; mt < 4; ++mt) d[m][mt] = (f32x4){0.f, 0.f, 0.f, 0.f};

#pragma unroll
        for (int h = 0; h < 2; ++h)
#pragma unroll
            for (int m = 0; m < 3; ++m)
#pragma unroll
                for (int mt = 0; mt < 4; ++mt) {
                    bf16x8 af = *reinterpret_cast<const bf16x8*>(
                        &Wl[(m * 64 + mt * 16 + l15) * 72 + h * 32 + quad * 8]);
                    d[m][mt] = __builtin_amdgcn_mfma_f32_16x16x32_bf16(af, bx[h], d[m][mt], 0, 0, 0);
                }

        const float* bias[3] = {bq, bk, bv};
        const float L2E = 1.44269504f;
#pragma unroll
        for (int m = 0; m < 3; ++m)
#pragma unroll
            for (int mt = 0; mt < 4; ++mt) {
                float4 bi = *reinterpret_cast<const float4*>(bias[m] + mt * 16 + quad * 4);
                d[m][mt][0] += bi.x; d[m][mt][1] += bi.y; d[m][mt][2] += bi.z; d[m][mt][3] += bi.w;
                if (m == 0) {
                    d[m][mt][0] *= L2E; d[m][mt][1] *= L2E;
                    d[m][mt][2] *= L2E; d[m][mt][3] *= L2E;
                }
            }

        // Q store: old global fragment-chunk layout
        const int rowchunk = (n0 >> 4) + wv;
        {
            u16* baseQ = Qt + (size_t)b * 262144;
#pragma unroll
            for (int mt = 0; mt < 4; ++mt) {
                uint2 pk;
                pk.x = (unsigned)f2bf(d[0][mt][0]) | ((unsigned)f2bf(d[0][mt][1]) << 16);
                pk.y = (unsigned)f2bf(d[0][mt][2]) | ((unsigned)f2bf(d[0][mt][3]) << 16);
                *reinterpret_cast<uint2*>(
                    baseQ + ((size_t)(rowchunk * 8 + mt * 2 + (quad >> 1))) * 128 +
                    l15 * 8 + (quad & 1) * 4) = pk;
            }
        }
        // K store: tile-major, stride 5120; within-tile chunk = wv*8 + c>>3
        {
            u16* baseK = Kt + (size_t)b * 327680 + (size_t)(n0 >> 6) * 5120;
#pragma unroll
            for (int mt = 0; mt < 4; ++mt) {
                uint2 pk;
                pk.x = (unsigned)f2bf(d[1][mt][0]) | ((unsigned)f2bf(d[1][mt][1]) << 16);
                pk.y = (unsigned)f2bf(d[1][mt][2]) | ((unsigned)f2bf(d[1][mt][3]) << 16);
                *reinterpret_cast<uint2*>(
                    baseK + (size_t)(wv * 8 + mt * 2 + (quad >> 1)) * 128 +
                    l15 * 8 + (quad & 1) * 4) = pk;
            }
        }
#pragma unroll
        for (int mt = 0; mt < 4; ++mt)
#pragma unroll
            for (int r = 0; r < 4; ++r)
                vt[(mt * 16 + quad * 4 + r) * 72 + wv * 16 + l15] = f2bf(d[2][mt][r]);
        __syncthreads();
        {
            u16* Vb_st = Vm + (size_t)b * 262144;
            const int kt = n0 >> 6;
#pragma unroll
            for (int i = 0; i < 2; ++i) {
                int unit = t + i * 256;
                int f = unit >> 7, hq = (unit >> 4) & 7, cl = unit & 15;
                const u16* src = &vt[(f * 16 + cl) * 72 + hq * 8];
                uint4 v4 = *reinterpret_cast<const uint4*>(src);
                *reinterpret_cast<uint4*>(
                    Vb_st + ((size_t)((kt * 4 + f) * 8 + hq)) * 128 + cl * 8) = v4;
            }
        }
    } else {
        // ---------------- edge ----------------
        u16* Ae_s = sm;            // [32][584]
        u16* xr_s = sm + 18688;    // [3][66][72]
        const int eb = blockIdx.x - 256;
        const int b = eb >> 6, h = eb & 63;

        if (t < 192) {
            int kh = t / 64, rem = t & 63;
            int col = (rem >> 5) * 65, ci2 = (rem & 31) * 2;
            *reinterpret_cast<unsigned*>(&xr_s[(kh * 66 + col) * 72 + ci2]) = 0u;
        }
#pragma unroll
        for (int i = 0; i < 18; ++i) {
            int u = t + i * 256;
            int ch = u / 144;
            int rem = u - ch * 144;
            int p = rem >> 4, cig = (rem & 15) * 4;
            const float* src = We1 + ch * 576 + cig * 9 + p;
            float a = src[0], b2 = src[9], c2 = src[18], d2 = src[27];
            uint2 pk;
            pk.x = (unsigned)f2bf(a) | ((unsigned)f2bf(b2) << 16);
            pk.y = (unsigned)f2bf(c2) | ((unsigned)f2bf(d2) << 16);
            *reinterpret_cast<uint2*>(&Ae_s[ch * 584 + p * 64 + cig]) = pk;
        }
#pragma unroll
        for (int i = 0; i < 12; ++i) {
            int u = t + i * 256;
            int w = u & 63, cig = (u >> 6) & 15, kh = u >> 10;
            int hs = h + kh - 1;
            float v0 = 0.f, v1 = 0.f, v2 = 0.f, v3 = 0.f;
            if ((unsigned)hs < 64u) {
                const float* src = x + ((size_t)(b * 64 + cig * 4) * 64 + hs) * 64 + w;
                v0 = src[0]; v1 = src[4096]; v2 = src[8192]; v3 = src[12288];
            }
            uint2 pk;
            pk.x = (unsigned)f2bf(v0) | ((unsigned)f2bf(v1) << 16);
            pk.y = (unsigned)f2bf(v2) | ((unsigned)f2bf(v3) << 16);
            *reinterpret_cast<uint2*>(&xr_s[(kh * 66 + w + 1) * 72 + cig * 4]) = pk;
        }
        __syncthreads();

        f32x4 e[2];
        e[0] = (f32x4){0.f, 0.f, 0.f, 0.f};
        e[1] = (f32x4){0.f, 0.f, 0.f, 0.f};
#pragma unroll
        for (int p = 0; p < 9; ++p) {
            const int kh = p / 3, kw = p - kh * 3;
#pragma unroll
            for (int half = 0; half < 2; ++half) {
                bf16x8 bfr = *reinterpret_cast<const bf16x8*>(
                    &xr_s[(kh * 66 + wv * 16 + l15 + kw) * 72 + half * 32 + quad * 8]);
#pragma unroll
                for (int mt = 0; mt < 2; ++mt) {
                    bf16x8 af = *reinterpret_cast<const bf16x8*>(
                        &Ae_s[(mt * 16 + l15) * 584 + p * 64 + half * 32 + quad * 8]);
                    e[mt] = __builtin_amdgcn_mfma_f32_16x16x32_bf16(af, bfr, e[mt], 0, 0, 0);
                }
            }
        }
        float partial = 0.f;
#pragma unroll
        for (int mt = 0; mt < 2; ++mt) {
            float4 bw = *reinterpret_cast<const float4*>(bn_w    + mt * 16 + quad * 4);
            float4 bb = *reinterpret_cast<const float4*>(bn_b    + mt * 16 + quad * 4);
            float4 bm = *reinterpret_cast<const float4*>(bn_mean + mt * 16 + quad * 4);
            float4 bv2 = *reinterpret_cast<const float4*>(bn_var + mt * 16 + quad * 4);
            float4 b1 = *reinterpret_cast<const float4*>(be1     + mt * 16 + quad * 4);
            float4 w2 = *reinterpret_cast<const float4*>(We2     + mt * 16 + quad * 4);
            float sc, sh;
            sc = bw.x * rsqrtf(bv2.x + 1e-5f); sh = (b1.x - bm.x) * sc + bb.x;
            partial += fmaxf(e[mt][0] * sc + sh, 0.f) * w2.x;
            sc = bw.y * rsqrtf(bv2.y + 1e-5f); sh = (b1.y - bm.y) * sc + bb.y;
            partial += fmaxf(e[mt][1] * sc + sh, 0.f) * w2.y;
            sc = bw.z * rsqrtf(bv2.z + 1e-5f); sh = (b1.z - bm.z) * sc + bb.z;
            partial += fmaxf(e[mt][2] * sc + sh, 0.f) * w2.z;
            sc = bw.w * rsqrtf(bv2.w + 1e-5f); sh = (b1.w - bm.w) * sc + bb.w;
            partial += fmaxf(e[mt][3] * sc + sh, 0.f) * w2.w;
        }
        partial += __shfl_xor(partial, 16);
        partial += __shfl_xor(partial, 32);
        if (lane < 16) {
            float s = partial + be2[0];
            float sg = 1.f / (1.f + __expf(-s));
            // 5th-chunk write: ch64 = lw' = log2(1+beta*sig), ch65 = 1.0.
            float lwp = __log2f(fmaxf(1.f + beta[0] * sg, 1e-20f));
            u16* k5 = Kt + (size_t)b * 327680 + (size_t)h * 5120 + 4096 +
                      (wv >> 1) * 512 + (wv & 1) * 256 + lane * 8;
            uint4 st0;
            st0.x = (unsigned)f2bf(lwp) | 0x3F800000u;  // {lw', 1.0}
            st0.y = 0u; st0.z = 0u; st0.w = 0u;
            *reinterpret_cast<uint4*>(k5) = st0;
            uint4 z; z.x = 0u; z.y = 0u; z.z = 0u; z.w = 0u;
            *reinterpret_cast<uint4*>(k5 + 128) = z;   // hi=1 half: zeros
        }
    }
}

// ------------------------------------------------------------- attention ---
// grid 128*NSPLIT(=1024); 256 thr = 4 waves x 32 q rows (QBLK=128), 8 kt-iters
// of 64 keys. 32x32x16 MFMA; swapped QK^T; P->B-frag via cvt_pk+permlane32.
// r21: LDS double-buffer staging (global_load_lds w=16; waves 0-1 K, 2-3 V);
// per-half-tile [QK -> softmax -> PV]; softmax in 8-elem halves so the arch
// register half of the (256,4) 64/64 split never exceeds ~46 live regs
// (s and o stay AGPR-resident). One __syncthreads per iter.
__global__ __launch_bounds__(256, 4) void attn_kernel(
    const u16* __restrict__ Qt, const u16* __restrict__ Kt,
    const u16* __restrict__ Vm,
    u16* __restrict__ O_part, float* __restrict__ l_part)
{
    constexpr int KT_ITERS = 64 / NSPLIT;   // 8
    __shared__ __align__(16) u16 kv[2][9216];   // [buf][ K 5120 | V 4096 ]

    // bijective XCD swizzle: 1024 blocks, 8 XCDs -> contiguous 128-block chunks
    const int bid = ((blockIdx.x & 7) << 7) + (blockIdx.x >> 3);
    const int t = threadIdx.x;
    const int qi = bid / NSPLIT;            // 0..127: (b, 128-q group)
    const int split = bid % NSPLIT;
    const int b = qi >> 5;
    const int n0 = (qi & 31) << 7;
    const int wv = t >> 6, lane = t & 63;
    const int l31 = lane & 31, hi = lane >> 5;
    const int i4 = (lane >> 4) & 1, l15 = lane & 15;

    const int kvoff = i4 * 1024 + hi * 128 + l15 * 8;   // within 4096-elem tile
    const int k5off = i4 * 256 + hi * 128 + l15 * 8;    // within 1024-elem chunk
    const u16* Qb  = Qt + (size_t)b * 262144;
    const u16* Ksp = Kt + (size_t)b * 327680 + (size_t)(split * KT_ITERS) * 5120;
    const u16* Vsp = Vm + (size_t)b * 262144 + (size_t)(split * KT_ITERS) * 4096;

    // Q B-frags: col=q=n0+wv*32+l31, k-chunk kc
    bf16x8 qf[4];
#pragma unroll
    for (int kc = 0; kc < 4; ++kc)
        qf[kc] = __builtin_bit_cast(bf16x8, *reinterpret_cast<const uint4*>(
            Qb + (size_t)(((n0 >> 4) + wv * 2) * 1024) + kvoff + kc * 256));
    // constant Q frag for the lw chunk: ch64 = 1.0, ch65 = -17.25 (bf16-exact)
    uint4 qc5u;
    qc5u.x = hi ? 0u : 0xC18A3F80u;
    qc5u.y = 0u; qc5u.z = 0u; qc5u.w = 0u;
    const bf16x8 qc5 = __builtin_bit_cast(bf16x8, qc5u);

    // stage tile `tile` (0..7) into buffer buf: waves 0-1 K (640 x 16B units),
    // waves 2-3 V (512 units). LDS dest linear in lane (global_load_lds rule).
    auto STAGE = [&](int buf, int tile) {
        if (wv < 2) {
            const u16* Kg = Ksp + (size_t)tile * 5120 + (wv * 320 + lane) * 8;
            u16* Kl = &kv[buf][(wv * 320 + lane) * 8];
#pragma unroll
            for (int i = 0; i < 5; ++i)
                gl_lds16(Kg + i * 512, Kl + i * 512);
        } else {
            const u16* Vg = Vsp + (size_t)tile * 4096 + ((wv - 2) * 256 + lane) * 8;
            u16* Vl = &kv[buf][5120 + ((wv - 2) * 256 + lane) * 8];
#pragma unroll
            for (int i = 0; i < 4; ++i)
                gl_lds16(Vg + i * 512, Vl + i * 512);
        }
    };

    f32x16 o[2];      // [c-tile of 32]: O^T[c][q]  (AGPR-resident)
#pragma unroll
    for (int ct = 0; ct < 2; ++ct)
#pragma unroll
        for (int i = 0; i < 16; ++i) o[ct][i] = 0.f;
    float lacc = 0.f;

    STAGE(0, 0);
    __syncthreads();    // implicit vmcnt(0): tile 0 resident

    int cur = 0;
    for (int kt = 0; kt < KT_ITERS; ++kt) {
        if (kt + 1 < KT_ITERS) STAGE(cur ^ 1, kt + 1);

        const u16* Kl = &kv[cur][0];
        const u16* Vl = &kv[cur][5120];

        // per 32-key half-tile: QK^T -> softmax(8-wide halves) -> PV.
        // s = K.q + lw' - 17.25 via the 5th chunk.
#pragma unroll
        for (int tl = 0; tl < 2; ++tl) {
            bf16x8 k4 = *reinterpret_cast<const bf16x8*>(Kl + 4096 + tl * 512 + k5off);
            bf16x8 k0 = *reinterpret_cast<const bf16x8*>(Kl + tl * 2048 + kvoff);
            bf16x8 k1 = *reinterpret_cast<const bf16x8*>(Kl + tl * 2048 + 256 + kvoff);
            bf16x8 k2 = *reinterpret_cast<const bf16x8*>(Kl + tl * 2048 + 512 + kvoff);
            bf16x8 k3 = *reinterpret_cast<const bf16x8*>(Kl + tl * 2048 + 768 + kvoff);
            f32x16 s;
#pragma unroll
            for (int i = 0; i < 16; ++i) s[i] = 0.f;
            __builtin_amdgcn_s_setprio(1);
            s = __builtin_amdgcn_mfma_f32_32x32x16_bf16(k4, qc5,   s, 0, 0, 0);
            s = __builtin_amdgcn_mfma_f32_32x32x16_bf16(k0, qf[0], s, 0, 0, 0);
            s = __builtin_amdgcn_mfma_f32_32x32x16_bf16(k1, qf[1], s, 0, 0, 0);
            s = __builtin_amdgcn_mfma_f32_32x32x16_bf16(k2, qf[2], s, 0, 0, 0);
            s = __builtin_amdgcn_mfma_f32_32x32x16_bf16(k3, qf[3], s, 0, 0, 0);
            __builtin_amdgcn_s_setprio(0);

            // softmax in 8-elem halves: only 8 p-values live at a time
            // (s stays AGPR-resident; arch half holds just p0..p7 + pb)
            uint4 pb0, pb1;
#pragma unroll
            for (int kc2 = 0; kc2 < 2; ++kc2) {
                float p0 = exp2f(s[kc2 * 8 + 0]);
                float p1 = exp2f(s[kc2 * 8 + 1]);
                float p2 = exp2f(s[kc2 * 8 + 2]);
                float p3 = exp2f(s[kc2 * 8 + 3]);
                float p4 = exp2f(s[kc2 * 8 + 4]);
                float p5 = exp2f(s[kc2 * 8 + 5]);
                float p6 = exp2f(s[kc2 * 8 + 6]);
                float p7 = exp2f(s[kc2 * 8 + 7]);
                lacc += ((p0 + p1) + (p2 + p3)) + ((p4 + p5) + (p6 + p7));
                int a0, a1, b0, b1;
                asm("v_cvt_pk_bf16_f32 %0, %1, %2" : "=v"(a0) : "v"(p0), "v"(p1));
                asm("v_cvt_pk_bf16_f32 %0, %1, %2" : "=v"(a1) : "v"(p2), "v"(p3));
                asm("v_cvt_pk_bf16_f32 %0, %1, %2" : "=v"(b0) : "v"(p4), "v"(p5));
                asm("v_cvt_pk_bf16_f32 %0, %1, %2" : "=v"(b1) : "v"(p6), "v"(p7));
                auto swA = __builtin_amdgcn_permlane32_swap(a0, b0, false, false);
                auto swB = __builtin_amdgcn_permlane32_swap(a1, b1, false, false);
                uint4 fr;
                fr.x = (unsigned)swA[0];   // keys hi*8 + 0,1
                fr.y = (unsigned)swB[0];   // keys hi*8 + 2,3
                fr.z = (unsigned)swA[1];   // keys hi*8 + 4,5
                fr.w = (unsigned)swB[1];   // keys hi*8 + 6,7
                if (kc2 == 0) pb0 = fr; else pb1 = fr;
            }

            // PV for this half-tile: key chunks tl*2+kc2
            __builtin_amdgcn_s_setprio(1);
#pragma unroll
            for (int ct = 0; ct < 2; ++ct) {
                bf16x8 va = *reinterpret_cast<const bf16x8*>(
                    Vl + ct * 2048 + (tl * 2 + 0) * 256 + kvoff);
                bf16x8 vb = *reinterpret_cast<const bf16x8*>(
                    Vl + ct * 2048 + (tl * 2 + 1) * 256 + kvoff);
                o[ct] = __builtin_amdgcn_mfma_f32_32x32x16_bf16(va,
                            __builtin_bit_cast(bf16x8, pb0), o[ct], 0, 0, 0);
                o[ct] = __builtin_amdgcn_mfma_f32_32x32x16_bf16(vb,
                            __builtin_bit_cast(bf16x8, pb1), o[ct], 0, 0, 0);
            }
            __builtin_amdgcn_s_setprio(0);
        }

        __syncthreads();   // stage(next) drained + all waves done with cur
        cur ^= 1;
    }

    // l: lane (hi,q) holds half the keys' sum; combine halves via shfl_xor(32)
    float ltot = lacc + __shfl_xor(lacc, 32);
    if (lane < 32)
        l_part[(size_t)bid * 128 + wv * 32 + lane] = ltot;

    // O^T[c][q]: c = ct*32 + g*8 + hi*4 + rr, q = wv*32 + l31
    // store layout: O_part[bid*8192 + (c>>2)*512 + q*4 + (c&3)]
    const size_t pbase = (size_t)bid * 8192;
    const int q = wv * 32 + l31;
#pragma unroll
    for (int ct = 0; ct < 2; ++ct)
#pragma unroll
        for (int g = 0; g < 4; ++g) {
            int w0, w1;
            asm("v_cvt_pk_bf16_f32 %0, %1, %2" : "=v"(w0) : "v"(o[ct][4 * g + 0]), "v"(o[ct][4 * g + 1]));
            asm("v_cvt_pk_bf16_f32 %0, %1, %2" : "=v"(w1) : "v"(o[ct][4 * g + 2]), "v"(o[ct][4 * g + 3]));
            uint2 pk2;
            pk2.x = (unsigned)w0;
            pk2.y = (unsigned)w1;
            *reinterpret_cast<uint2*>(
                &O_part[pbase + (size_t)(ct * 8 + g * 2 + hi) * 512 + q * 4]) = pk2;
        }
}

// ---------------------------------------------------------------- combine --
// grid 512: one 32-q slice per block (2 blocks/CU). ab = attn qi (128-q),
// sub = which 32-q quarter. LDS stride 65 -> conflict-free scalar access.
__global__ __launch_bounds__(256) void combine_kernel(
    const u16* __restrict__ O_part, const float* __restrict__ l_part,
    const float* __restrict__ x, const float* __restrict__ g_gamma,
    float* __restrict__ out)
{
    __shared__ float ot[32 * 65];   // [q-local][c]
    __shared__ float ls[32];
    const int t = threadIdx.x;
    const int ab = blockIdx.x >> 2;
    const int sub = blockIdx.x & 3;
    const int b = ab >> 5;
    const int n0 = (ab & 31) << 7;
    const float gamma = g_gamma[0];

#pragma unroll
    for (int i = 0; i < 2; ++i) {
        int idx = t + i * 256;
        int c4 = idx >> 5, ql = idx & 31;
        float a0 = 0.f, a1 = 0.f, a2 = 0.f, a3 = 0.f;
#pragma unroll
        for (int s4 = 0; s4 < NSPLIT; ++s4) {
            uint2 u = *reinterpret_cast<const uint2*>(
                O_part + ((size_t)(ab * NSPLIT + s4)) * 8192 +
                (size_t)c4 * 512 + (sub * 32 + ql) * 4);
            a0 += bf2f((u16)(u.x & 0xFFFF));
            a1 += bf2f((u16)(u.x >> 16));
            a2 += bf2f((u16)(u.y & 0xFFFF));
            a3 += bf2f((u16)(u.y >> 16));
        }
        ot[ql * 65 + c4 * 4 + 0] = a0;
        ot[ql * 65 + c4 * 4 + 1] = a1;
        ot[ql * 65 + c4 * 4 + 2] = a2;
        ot[ql * 65 + c4 * 4 + 3] = a3;
    }
    if (t < 32) {
        float lsum = 0.f;
#pragma unroll
        for (int s4 = 0; s4 < NSPLIT; ++s4)
            lsum += l_part[((size_t)(ab * NSPLIT + s4)) * 128 + sub * 32 + t];
        ls[t] = gamma / fmaxf(lsum, 1e-30f);
    }
    __syncthreads();
    {
        const int c = t >> 2, seg = t & 3;
        const size_t gbase = ((size_t)(b * 64 + c)) * 4096 + n0 + sub * 32 + seg * 8;
#pragma unroll
        for (int j = 0; j < 2; ++j) {
            float4 xv = *reinterpret_cast<const float4*>(&x[gbase + j * 4]);
            float4 rv;
            int nl = seg * 8 + j * 4;
            rv.x = ot[(nl + 0) * 65 + c] * ls[nl + 0] + xv.x;
            rv.y = ot[(nl + 1) * 65 + c] * ls[nl + 1] + xv.y;
            rv.z = ot[(nl + 2) * 65 + c] * ls[nl + 2] + xv.z;
            rv.w = ot[(nl + 3) * 65 + c] * ls[nl + 3] + xv.w;
            *reinterpret_cast<float4*>(&out[gbase + j * 4]) = rv;
        }
    }
}

// ---------------------------------------------------------------- launch ---
extern "C" void kernel_launch(void* const* d_in, const int* in_sizes, int n_in,
                              void* d_out, int out_size, void* d_ws, size_t ws_size,
                              hipStream_t stream) {
    const float* x      = (const float*)d_in[0];
    const float* Wq     = (const float*)d_in[1];
    const float* bq     = (const float*)d_in[2];
    const float* Wk     = (const float*)d_in[3];
    const float* bk     = (const float*)d_in[4];
    const float* Wv     = (const float*)d_in[5];
    const float* bv     = (const float*)d_in[6];
    const float* We1    = (const float*)d_in[7];
    const float* be1    = (const float*)d_in[8];
    const float* bn_w   = (const float*)d_in[9];
    const float* bn_b   = (const float*)d_in[10];
    const float* bn_mean= (const float*)d_in[11];
    const float* bn_var = (const float*)d_in[12];
    const float* We2    = (const float*)d_in[13];
    const float* be2    = (const float*)d_in[14];
    const float* gamma  = (const float*)d_in[15];
    const float* beta   = (const float*)d_in[16];

    char* ws = (char*)d_ws;
    const size_t MB = 1024 * 1024;
    u16*   Qt     = (u16*)ws;                // [0, 2 MB)
    u16*   Kt     = (u16*)(ws + 2 * MB);     // [2, 4.625 MB) 4 x 327680 u16
    u16*   Vm     = (u16*)(ws + 5 * MB);     // [5, 7 MB)
    float* l_part = (float*)(ws + 7 * MB);   // 512 KB (1024 blk x 128)
    u16*   O_part = (u16*)(ws + 8 * MB);     // 16.78 MB (1024 x 8192)

    float* out = (float*)d_out;

    qkv_edge_kernel<<<dim3(512), dim3(256), 0, stream>>>(
        x, Wq, bq, Wk, bk, Wv, bv, We1, be1, bn_w, bn_b, bn_mean, bn_var,
        We2, be2, beta, Qt, Kt, Vm);
    attn_kernel<<<dim3(128 * NSPLIT), dim3(256), 0, stream>>>(
        Qt, Kt, Vm, O_part, l_part);
    combine_kernel<<<dim3(512), dim3(256), 0, stream>>>(
        O_part, l_part, x, gamma, out);
}